// Round 15
// baseline (286.590 us; speedup 1.0000x reference)
//
#include <hip/hip_runtime.h>
#include <hip/hip_bf16.h>

// ---------------------------------------------------------------------------
// DRRGHead, 7 dispatches.
//   relu(cat(x_norm, A@x_norm) @ W + b) == relu(x@W' + b' + A@(x@W'_bot))
// BN folded into W1. GEMM+agg fused per layer: M-tile = 3 graphs (123 rows
// pad 128), Bt rows permuted so each 128-col tile = 64 L-cols + 64 R-cols;
// P stays in LDS; y = relu(P_L + A@P_R) written directly.
// R15: (a) conv pool INTERLEAVED into L1 grid (odd bids) -> conv HBM work
//   overlaps latency-bound GEMM phase instead of trailing; (b) adjacency
//   staged ONE GRAPH AT A TIME (7.2KB @ 32768, outside Psh overlay): LDS
//   53.1KB -> 40.0KB -> 4 blocks/CU (16 waves, 50% occupancy ceiling).
// GEMM core: 128x128, 2-ph dbuf global_load_lds, conflict-free slot-swizzle,
// supergroup swizzle.
// ---------------------------------------------------------------------------

using f32x4 = __attribute__((ext_vector_type(4))) float;
using s16x8 = __attribute__((ext_vector_type(8))) short;   // 8 bf16

#define GN 20992          // G*N rows
#define NFEAT 576
#define NGRAPH 512
#define NNODE 41
#define ASTR 44           // padded A row stride (44 f32 = 176 B, 16B-aligned)
#define NTMG 171          // m-tiles of 3 graphs (123 rows); 171*3 = 513 >= 512

typedef __attribute__((address_space(1))) const unsigned int gas_u32;
typedef __attribute__((address_space(3))) unsigned int las_u32;

__device__ __forceinline__ void gl_lds16(const void* g, void* l) {
  __builtin_amdgcn_global_load_lds((gas_u32*)g, (las_u32*)l, 16, 0, 0);
}

// dot over 41: A row (LDS, 16B-aligned, broadcast) . pr[] (regs), float4 reads
__device__ __forceinline__ float dot41_f4(const float* __restrict__ Am,
                                          const float* __restrict__ pr) {
  float s0 = 0.f, s1 = 0.f, s2 = 0.f, s3 = 0.f;
#pragma unroll
  for (int q = 0; q < 10; ++q) {
    float4 a4 = *(const float4*)(Am + q * 4);
    s0 += a4.x * pr[q * 4];
    s1 += a4.y * pr[q * 4 + 1];
    s2 += a4.z * pr[q * 4 + 2];
    s3 += a4.w * pr[q * 4 + 3];
  }
  return ((s0 + s1) + (s2 + s3)) + Am[40] * pr[40];
}

// ---------------- K1: fused bf16-cast + bn-stats (one pass over nf) ---------
__global__ __launch_bounds__(576) void front_kernel(
    const float* __restrict__ nf, float* __restrict__ partial,
    __hip_bfloat16* __restrict__ x0) {
  int c = threadIdx.x;                  // 0..575
  int u = blockIdx.x;                   // 0..255
  int r0 = u * 82;
  const float* src = nf + (size_t)r0 * NFEAT + c;
  __hip_bfloat16* dst = x0 + (size_t)r0 * NFEAT + c;
  float s = 0.f, s2 = 0.f;
#pragma unroll 4
  for (int r = 0; r < 82; ++r) {
    float v = src[(size_t)r * NFEAT];
    s += v; s2 += v * v;
    dst[(size_t)r * NFEAT] = __float2bfloat16(v);
  }
  partial[(size_t)u * 1152 + c] = s;
  partial[(size_t)u * 1152 + NFEAT + c] = s2;
}

// ---------------- K2: wide BN reduce -> statsbuf = {inv[576], m*inv[576]} ---
__global__ __launch_bounds__(256) void reduce_kernel(
    const float* __restrict__ partial, float* __restrict__ statsbuf) {
  int t = blockIdx.x * 256 + threadIdx.x;
  if (t >= NFEAT) return;
  float s = 0.f, s2 = 0.f;
#pragma unroll 8
  for (int u = 0; u < 256; ++u) {
    s += partial[(size_t)u * 1152 + t];
    s2 += partial[(size_t)u * 1152 + NFEAT + t];
  }
  float m = s * (1.f / GN);
  float v = s2 * (1.f / GN) - m * m;
  float inv = rsqrtf(v + 1e-5f);
  statsbuf[t] = inv;
  statsbuf[NFEAT + t] = m * inv;
}

// ---------------- K3: W1 fold-repack + cvec GEMV + W2-4 repack --------------
// All Bt writes use paired-col permutation jp = (rowh>>6)*128 + h*64 + (rowh&63)
__global__ __launch_bounds__(256) void wt1_kernel(
    const float* __restrict__ W1, const float* __restrict__ b1,
    const float* __restrict__ statsbuf, __hip_bfloat16* __restrict__ B1,
    float* __restrict__ gbias,
    const float* __restrict__ W2, const float* __restrict__ W3,
    const float* __restrict__ W4,
    __hip_bfloat16* __restrict__ B2, __hip_bfloat16* __restrict__ B3,
    __hip_bfloat16* __restrict__ B4) {
  int u = blockIdx.x;
  int tid = threadIdx.x;
  if (u < 576) {                        // fold-repack tile of W1 (2N=1024,K=576)
    __shared__ float T[32 * 33];
    int jt = u / 18, kt = u - jt * 18;
    int j0 = jt * 32, k0 = kt * 32;
    int h = (j0 >= 512) ? 1 : 0;
    const float* Wh = W1 + (size_t)(h * 576) * 512 + (j0 - h * 512);
    int r = tid >> 5, cc = tid & 31;
#pragma unroll
    for (int i = 0; i < 4; ++i)
      T[(r + i * 8) * 33 + cc] = Wh[(size_t)(k0 + r + i * 8) * 512 + cc];
    __syncthreads();
    float invv = statsbuf[k0 + cc];
#pragma unroll
    for (int i = 0; i < 4; ++i) {
      int rowh = (j0 - h * 512) + r + i * 8;
      int jp = (rowh >> 6) * 128 + h * 64 + (rowh & 63);
      B1[(size_t)jp * 576 + k0 + cc] =
          __float2bfloat16(T[cc * 33 + (r + i * 8)] * invv);
    }
  } else if (u < 580) {                 // cvec GEMV (gbias in ORIGINAL order)
    int j = (u - 576) * 256 + tid;      // 0..1023
    int col = (j < 512) ? j : j - 512;
    const float* base = W1 + (size_t)((j < 512) ? 0 : 576) * 512 + col;
    float s = 0.f;
#pragma unroll 4
    for (int f = 0; f < NFEAT; ++f) s += statsbuf[NFEAT + f] * base[(size_t)f * 512];
    gbias[j] = ((j < 512) ? b1[j] : 0.f) - s;
  } else {                              // plain repack W2/W3/W4 (permuted rows)
    __shared__ float T[32 * 33];
    int t = u - 580;
    const float* W; __hip_bfloat16* B; int K, N;
    if (t < 256)      { W = W2; B = B2; K = 512; N = 256; }
    else if (t < 320) { W = W3; B = B3; K = 256; N = 128; t -= 256; }
    else              { W = W4; B = B4; K = 128; N = 64;  t -= 320; }
    int tilesN = N >> 5;
    int perhalf = (K >> 5) * tilesN;
    int h = t / perhalf; t -= h * perhalf;
    int tk = t / tilesN, tn = t - tk * tilesN;
    int r = tid >> 5, cc = tid & 31;
    const float* Wh = W + (size_t)h * K * N;
#pragma unroll
    for (int i = 0; i < 4; ++i)
      T[(r + i * 8) * 33 + cc] = Wh[(size_t)(tk * 32 + r + i * 8) * N + tn * 32 + cc];
    __syncthreads();
#pragma unroll
    for (int i = 0; i < 4; ++i) {
      int row = tn * 32 + r + i * 8;
      int jp = (row >> 6) * 128 + h * 64 + (row & 63);
      B[(size_t)jp * K + tk * 32 + cc] =
          __float2bfloat16(T[cc * 33 + r + i * 8]);
    }
  }
}

// ---------------- fused GEMM + agg: y = relu(P_L + A@P_R), layers 1-3 -------
// M-tile = 3 graphs (123 rows pad 128); N-tile = 64 L-cols + 64 paired R-cols.
// P in LDS rows 0..122; Aash (one graph, 7.2KB) at [32768, 39984).
// convBlocks > 0 (L1): odd bids < 2*convBlocks run the 1x1-conv pool.
__global__ __launch_bounds__(256) void gemmagg_kernel(
    const __hip_bfloat16* __restrict__ Xptr, const __hip_bfloat16* __restrict__ Bt,
    const float* __restrict__ biasL, const float* __restrict__ biasR,
    __hip_bfloat16* __restrict__ Yptr, int Nout, int K, int NTN, int convBlocks,
    const float* __restrict__ Aadj,
    const float* __restrict__ cinputs, const float* __restrict__ conv_w,
    const float* __restrict__ conv_b, float* __restrict__ cout) {
  // LDS map: [0,32768) staging dbuf; Psh rows 0..127 overlay [0,32768);
  //          Aash (1 graph, 41 x 44 f32 = 7216 B) at [32768, 39984).
  __shared__ __align__(16) char smem[39984];
  short* AshD = (short*)smem;                 // [2][128*32]
  short* BshD = (short*)(smem + 16384);       // [2][128*32]
  __hip_bfloat16* Psh = (__hip_bfloat16*)smem;
  float* Aash = (float*)(smem + 32768);

  int tid = threadIdx.x;
  int bid = blockIdx.x;

  if (convBlocks > 0) {
    int twoC = convBlocks * 2;
    if (bid < twoC) {
      if (bid & 1) {                    // ---- conv pool (interleaved)
        int p = (bid >> 1) * 256 + tid;
        int img = p >> 16, q = p & 65535;
        const float4* ip = (const float4*)cinputs + (size_t)img * 32 * 65536 + q;
        float4 acc[6];
#pragma unroll
        for (int o = 0; o < 6; ++o) { float b0 = conv_b[o]; acc[o] = make_float4(b0, b0, b0, b0); }
#pragma unroll 4
        for (int c = 0; c < 32; ++c) {
          float4 x = ip[(size_t)c * 65536];
#pragma unroll
          for (int o = 0; o < 6; ++o) {
            float wv = conv_w[o * 32 + c];
            acc[o].x += x.x * wv; acc[o].y += x.y * wv;
            acc[o].z += x.z * wv; acc[o].w += x.w * wv;
          }
        }
        float4* op = (float4*)cout + (size_t)img * 6 * 65536 + q;
#pragma unroll
        for (int o = 0; o < 6; ++o) op[(size_t)o * 65536] = acc[o];
        return;
      }
      bid >>= 1;                        // even bids -> gemm ids 0..convBlocks-1
    } else {
      bid -= convBlocks;                // remaining gemm ids
    }
  }

  int sg = bid / (NTN * 8);
  int rem = bid - sg * (NTN * 8);
  int Wm = NTMG - sg * 8; if (Wm > 8) Wm = 8;
  int mt = sg * 8 + rem % Wm;
  int nt = rem / Wm;
  int row0 = mt * 123;
  int g0 = mt * 3;
  int gcnt = NGRAPH - g0; if (gcnt > 3) gcnt = 3;

  int wave = tid >> 6, lane = tid & 63;
  int wm = wave >> 1, wn = wave & 1;
  int lr = lane & 15, kb = lane >> 4;

  f32x4 acc[4][4];
#pragma unroll
  for (int m = 0; m < 4; ++m)
#pragma unroll
    for (int n = 0; n < 4; ++n) acc[m][n] = (f32x4){0.f, 0.f, 0.f, 0.f};

  const short* Ag = (const short*)Xptr;
  const short* Bg = (const short*)Bt + (size_t)nt * 128 * K;

  // staging: slot c holds global chunk (row = c>>2, k-chunk = (c&3)^((row>>1)&3))
  int c0 = tid, c1 = tid + 256;
  int ar0 = c0 >> 2, ak0 = (((c0 & 3) ^ ((ar0 >> 1) & 3))) * 8;
  int ar1 = c1 >> 2, ak1 = (((c1 & 3) ^ ((ar1 >> 1) & 3))) * 8;
  int grow0 = row0 + ar0; if (grow0 > GN - 1) grow0 = GN - 1;   // pad rows clamp
  int grow1 = row0 + ar1; if (grow1 > GN - 1) grow1 = GN - 1;

  // fragment read offsets (shorts): row*32 + (((row>>1)&3)^kb)*8
  int aoff[4], boff[4];
#pragma unroll
  for (int m = 0; m < 4; ++m) {
    int r = wm * 64 + m * 16 + lr;
    aoff[m] = r * 32 + ((((r >> 1) & 3) ^ kb) * 8);
  }
#pragma unroll
  for (int n = 0; n < 4; ++n) {
    int r = wn * 64 + n * 16 + lr;
    boff[n] = r * 32 + ((((r >> 1) & 3) ^ kb) * 8);
  }

  gl_lds16(Ag + (size_t)grow0 * K + ak0, &AshD[c0 * 8]);
  gl_lds16(Ag + (size_t)grow1 * K + ak1, &AshD[c1 * 8]);
  gl_lds16(Bg + (size_t)ar0 * K + ak0, &BshD[c0 * 8]);
  gl_lds16(Bg + (size_t)ar1 * K + ak1, &BshD[c1 * 8]);
  __syncthreads();

  int nkt = K >> 5;
  int cur = 0;
  for (int kt = 0; kt < nkt; ++kt) {
    if (kt + 1 < nkt) {
      int k1 = (kt + 1) * 32;
      int nxt = (cur ^ 1) * 4096;
      gl_lds16(Ag + (size_t)grow0 * K + k1 + ak0, &AshD[nxt + c0 * 8]);
      gl_lds16(Ag + (size_t)grow1 * K + k1 + ak1, &AshD[nxt + c1 * 8]);
      gl_lds16(Bg + (size_t)ar0 * K + k1 + ak0, &BshD[nxt + c0 * 8]);
      gl_lds16(Bg + (size_t)ar1 * K + k1 + ak1, &BshD[nxt + c1 * 8]);
    }
    int cb = cur * 4096;
    s16x8 af[4], bfr[4];
#pragma unroll
    for (int m = 0; m < 4; ++m) af[m] = *(const s16x8*)&AshD[cb + aoff[m]];
#pragma unroll
    for (int n = 0; n < 4; ++n) bfr[n] = *(const s16x8*)&BshD[cb + boff[n]];
#pragma unroll
    for (int m = 0; m < 4; ++m)
#pragma unroll
      for (int n = 0; n < 4; ++n)
        acc[m][n] = __builtin_amdgcn_mfma_f32_16x16x32_bf16(af[m], bfr[n], acc[m][n], 0, 0, 0);
    __syncthreads();
    cur ^= 1;
  }

  // epilogue 1: P (+bias, both halves) -> Psh overlay (safe: loop ended w/ barrier)
  int rbase = (lane >> 4) * 4;
#pragma unroll
  for (int m = 0; m < 4; ++m) {
    int lrow = wm * 64 + m * 16 + rbase;
#pragma unroll
    for (int n = 0; n < 4; ++n) {
      int w = wn * 64 + n * 16 + lr;
      float bv = (w < 64) ? biasL[nt * 64 + w]
                          : (biasR ? biasR[nt * 64 + (w - 64)] : 0.f);
#pragma unroll
      for (int r = 0; r < 4; ++r)
        Psh[(size_t)(lrow + r) * 128 + w] = __float2bfloat16(acc[m][n][r] + bv);
    }
  }
  // stage A for graph 0 (Aash disjoint from Psh -> one barrier covers both)
  {
    const float* Asrc = Aadj + (size_t)g0 * (NNODE * NNODE);
    for (int i = tid; i < NNODE * NNODE; i += 256) {
      int row = i / NNODE, m = i - row * NNODE;
      Aash[row * ASTR + m] = Asrc[i];
    }
  }
  __syncthreads();

  // epilogue 2: per graph: y[g][n][c] = relu(P_L[n][c] + dot(A[n,:], P_R[:,c]))
  int c = tid & 63, grp = tid >> 6;
  for (int g = 0; g < gcnt; ++g) {
    float pr[NNODE];
#pragma unroll
    for (int m = 0; m < NNODE; ++m)
      pr[m] = __bfloat162float(Psh[(size_t)(g * NNODE + m) * 128 + 64 + c]);
#pragma unroll 1
    for (int n = grp; n < NNODE; n += 4) {
      float aa = __bfloat162float(Psh[(size_t)(g * NNODE + n) * 128 + c])
               + dot41_f4(Aash + n * ASTR, pr);
      aa = aa > 0.f ? aa : 0.f;
      Yptr[(size_t)(row0 + g * NNODE + n) * Nout + nt * 64 + c] = __float2bfloat16(aa);
    }
    if (g + 1 < gcnt) {                 // swap Aash to next graph
      __syncthreads();                  // all reads of A_g done
      const float* Asrc = Aadj + (size_t)(g0 + g + 1) * (NNODE * NNODE);
      for (int i = tid; i < NNODE * NNODE; i += 256) {
        int row = i / NNODE, m = i - row * NNODE;
        Aash[row * ASTR + m] = Asrc[i];
      }
      __syncthreads();                  // A_{g+1} visible
    }
  }
}

// ---------------- G4F: gemm4 + agg4 + knn classifier, 3 graphs/block --------
__global__ __launch_bounds__(256) void gemm4cls_kernel(
    const __hip_bfloat16* __restrict__ X, const __hip_bfloat16* __restrict__ B4t,
    const float* __restrict__ b4, const float* __restrict__ Aadj,
    const int* __restrict__ knn, const float* __restrict__ w1,
    const float* __restrict__ cb1, const float* __restrict__ pa,
    const float* __restrict__ w2, const float* __restrict__ cb2,
    float* __restrict__ out) {
  __shared__ __align__(16) char smem[49152 + 21648 + 31488 + 8192 + 520];
  short* AshD = (short*)smem;
  short* Bsh  = (short*)(smem + 16384);
  __hip_bfloat16* Psh = (__hip_bfloat16*)smem;
  float* Aash = (float*)(smem + 49152);                   // 123 x 44 f32 padded
  float* Ysh  = (float*)(smem + 49152 + 21648);
  float* Wsh  = (float*)(smem + 49152 + 21648 + 31488);
  float* cb   = (float*)(smem + 49152 + 21648 + 31488 + 8192);

  int tid = threadIdx.x;
  int blk = blockIdx.x;
  int g0 = blk * 3;
  int gcnt = NGRAPH - g0; if (gcnt > 3) gcnt = 3;
  int row0 = blk * 123;

  {
    int tot = gcnt * (NNODE * NNODE);
    const float* Asrc = Aadj + (size_t)g0 * (NNODE * NNODE);
    for (int i = tid; i < tot; i += 256) {
      int row = i / NNODE, m = i - row * NNODE;
      Aash[row * ASTR + m] = Asrc[i];
    }
  }
  for (int i = tid; i < 2048; i += 256) Wsh[i] = w1[i];
  if (tid < 32) { cb[tid] = cb1[tid]; cb[32 + tid] = pa[tid]; }
  if (tid < 64) cb[64 + tid] = w2[tid];
  if (tid < 2) cb[128 + tid] = cb2[tid];

  // stage whole B4t (4 ktiles), slot-swizzled within each ktile
#pragma unroll
  for (int i = 0; i < 8; ++i) {
    int c = tid + i * 256;              // 2048 chunks of 16B
    int kt = c >> 9, w = c & 511;
    int r = w >> 2, kc = ((w & 3) ^ ((r >> 1) & 3)) * 8;
    gl_lds16((const short*)B4t + (size_t)r * 128 + kt * 32 + kc, &Bsh[c * 8]);
  }
  // stage A k-tile 0 (swizzled)
  const short* Ag = (const short*)X;
  int c0 = tid, c1 = tid + 256;
  int ar0 = c0 >> 2, ak0 = (((c0 & 3) ^ ((ar0 >> 1) & 3))) * 8;
  int ar1 = c1 >> 2, ak1 = (((c1 & 3) ^ ((ar1 >> 1) & 3))) * 8;
  int grow0 = row0 + ar0; if (grow0 > GN - 1) grow0 = GN - 1;
  int grow1 = row0 + ar1; if (grow1 > GN - 1) grow1 = GN - 1;
  gl_lds16(Ag + (size_t)grow0 * 128 + ak0, &AshD[c0 * 8]);
  gl_lds16(Ag + (size_t)grow1 * 128 + ak1, &AshD[c1 * 8]);
  __syncthreads();

  int wave = tid >> 6, lane = tid & 63;
  int wm = wave >> 1, wn = wave & 1;
  int lr = lane & 15, kb = lane >> 4;
  int aoff[4], boff[4];
#pragma unroll
  for (int m = 0; m < 4; ++m) {
    int r = wm * 64 + m * 16 + lr;
    aoff[m] = r * 32 + ((((r >> 1) & 3) ^ kb) * 8);
  }
#pragma unroll
  for (int n = 0; n < 4; ++n) {
    int r = wn * 64 + n * 16 + lr;
    boff[n] = r * 32 + ((((r >> 1) & 3) ^ kb) * 8);
  }
  f32x4 acc[4][4];
#pragma unroll
  for (int m = 0; m < 4; ++m)
#pragma unroll
    for (int n = 0; n < 4; ++n) acc[m][n] = (f32x4){0.f, 0.f, 0.f, 0.f};

  int cur = 0;
  for (int kt = 0; kt < 4; ++kt) {
    if (kt < 3) {
      int k1 = (kt + 1) * 32;
      int nxt = (cur ^ 1) * 4096;
      gl_lds16(Ag + (size_t)grow0 * 128 + k1 + ak0, &AshD[nxt + c0 * 8]);
      gl_lds16(Ag + (size_t)grow1 * 128 + k1 + ak1, &AshD[nxt + c1 * 8]);
    }
    int cbse = cur * 4096;
    s16x8 af[4], bfr[4];
#pragma unroll
    for (int m = 0; m < 4; ++m) af[m] = *(const s16x8*)&AshD[cbse + aoff[m]];
#pragma unroll
    for (int n = 0; n < 4; ++n) bfr[n] = *(const s16x8*)&Bsh[kt * 4096 + boff[n]];
#pragma unroll
    for (int m = 0; m < 4; ++m)
#pragma unroll
      for (int n = 0; n < 4; ++n)
        acc[m][n] = __builtin_amdgcn_mfma_f32_16x16x32_bf16(af[m], bfr[n], acc[m][n], 0, 0, 0);
    __syncthreads();
    cur ^= 1;
  }
  // epilogue -> Psh
  int rbase = (lane >> 4) * 4;
#pragma unroll
  for (int m = 0; m < 4; ++m) {
    int lrow = wm * 64 + m * 16 + rbase;
#pragma unroll
    for (int n = 0; n < 4; ++n) {
      int col = wn * 64 + n * 16 + lr;
      float bv = (col < 64) ? b4[col] : 0.f;
#pragma unroll
      for (int r = 0; r < 4; ++r)
        Psh[(size_t)(lrow + r) * 128 + col] = __float2bfloat16(acc[m][n][r] + bv);
    }
  }
  __syncthreads();

  // agg into Ysh (float4 broadcast dot)
  int c = tid & 63, grp = tid >> 6;
  for (int g = 0; g < gcnt; ++g) {
    float pr[NNODE];
#pragma unroll
    for (int m = 0; m < NNODE; ++m)
      pr[m] = __bfloat162float(Psh[(size_t)(g * NNODE + m) * 128 + 64 + c]);
#pragma unroll 1
    for (int n = grp; n < NNODE; n += 4) {
      float aa = __bfloat162float(Psh[(size_t)(g * NNODE + n) * 128 + c])
               + dot41_f4(Aash + (g * NNODE + n) * ASTR, pr);
      Ysh[(g * NNODE + n) * 64 + c] = aa > 0.f ? aa : 0.f;
    }
  }
  __syncthreads();

  // classifier: 8*gcnt edges, 32 lanes each
  int j = tid & 31, slot = tid >> 5;
  for (int el = slot; el < 8 * gcnt; el += 8) {
    int e = g0 * 8 + el;
    int node = knn[e];
    int gl = el >> 3;
    const float* fp = &Ysh[(gl * NNODE + node) * 64];
    float a2 = cb[j];
#pragma unroll
    for (int d = 0; d < 64; ++d) a2 += fp[d] * Wsh[d * 32 + j];
    float h = a2 >= 0.f ? a2 : cb[32 + j] * a2;
#pragma unroll
    for (int o = 0; o < 2; ++o) {
      float v = h * cb[64 + j * 2 + o];
      v += __shfl_xor(v, 16, 32); v += __shfl_xor(v, 8, 32);
      v += __shfl_xor(v, 4, 32);  v += __shfl_xor(v, 2, 32);
      v += __shfl_xor(v, 1, 32);
      if (j == 0) out[(size_t)e * 2 + o] = v;
    }
  }
}

// ---------------------------------------------------------------------------
extern "C" void kernel_launch(void* const* d_in, const int* in_sizes, int n_in,
                              void* d_out, int out_size, void* d_ws, size_t ws_size,
                              hipStream_t stream) {
  const float* inputs     = (const float*)d_in[0];
  const float* node_feats = (const float*)d_in[1];
  const float* Aadj       = (const float*)d_in[2];
  const int*   knn        = (const int*)d_in[3];
  const float* conv_w     = (const float*)d_in[4];
  const float* conv_b     = (const float*)d_in[5];
  const float* W1 = (const float*)d_in[6];  const float* b1 = (const float*)d_in[7];
  const float* W2 = (const float*)d_in[8];  const float* b2 = (const float*)d_in[9];
  const float* W3 = (const float*)d_in[10]; const float* b3 = (const float*)d_in[11];
  const float* W4 = (const float*)d_in[12]; const float* b4 = (const float*)d_in[13];
  const float* cls_w1 = (const float*)d_in[14]; const float* cls_b1 = (const float*)d_in[15];
  const float* prelu_a = (const float*)d_in[16];
  const float* cls_w2 = (const float*)d_in[17]; const float* cls_b2 = (const float*)d_in[18];
  float* out = (float*)d_out;

  char* ws = (char*)d_ws;
  char* R1 = ws;                        // x0 (24.2 MB) -> y2 (10.7 MB)
  char* R2 = ws + 24200192;             // y1 (21.5 MB) -> y3 (5.4 MB)
  char* wp = ws + 24200192 + 42991616;
  __hip_bfloat16* B1t = (__hip_bfloat16*)wp;  wp += 1179648;   // 1024 x 576
  __hip_bfloat16* B2t = (__hip_bfloat16*)wp;  wp += 524288;    // 512 x 512
  __hip_bfloat16* B3t = (__hip_bfloat16*)wp;  wp += 131072;    // 256 x 256
  __hip_bfloat16* B4t = (__hip_bfloat16*)wp;  wp += 32768;     // 128 x 128
  float* partial  = (float*)wp;               wp += 256 * 1152 * 4;
  float* statsbuf = (float*)wp;               wp += 1152 * 4;
  float* gbias    = (float*)wp;               wp += 1024 * 4;

  __hip_bfloat16* x0 = (__hip_bfloat16*)R1;

  // K1: fused cast + stats (one pass over node_feats)
  front_kernel<<<256, 576, 0, stream>>>(node_feats, partial, x0);
  // K2: wide BN reduce
  reduce_kernel<<<3, 256, 0, stream>>>(partial, statsbuf);
  // K3: W1 fold-repack + cvec GEMV + W2-4 repack (paired-col permutation)
  wt1_kernel<<<932, 256, 0, stream>>>(W1, b1, statsbuf, B1t, gbias,
                                      W2, W3, W4, B2t, B3t, B4t);

  // L1 fused gemm+agg, conv interleaved: x0 -> y1 (R2), Nout=512, K=576, NTN=8
  gemmagg_kernel<<<NTMG * 8 + 1024, 256, 0, stream>>>(
      x0, B1t, gbias, gbias + 512, (__hip_bfloat16*)R2, 512, 576, 8, 1024,
      Aadj, inputs, conv_w, conv_b, out);
  // L2: y1 -> y2 (R1), Nout=256, K=512, NTN=4
  gemmagg_kernel<<<NTMG * 4, 256, 0, stream>>>(
      (__hip_bfloat16*)R2, B2t, b2, nullptr, (__hip_bfloat16*)R1, 256, 512, 4,
      0, Aadj, nullptr, nullptr, nullptr, nullptr);
  // L3: y2 -> y3 (R2), Nout=128, K=256, NTN=2
  gemmagg_kernel<<<NTMG * 2, 256, 0, stream>>>(
      (__hip_bfloat16*)R1, B3t, b3, nullptr, (__hip_bfloat16*)R2, 128, 256, 2,
      0, Aadj, nullptr, nullptr, nullptr, nullptr);
  // L4 fused: gemm + agg + knn classifier
  gemm4cls_kernel<<<171, 256, 0, stream>>>(
      (__hip_bfloat16*)R2, B4t, b4, Aadj, knn, cls_w1, cls_b1, prelu_a,
      cls_w2, cls_b2, out + 6291456);
}

// Round 16
// 247.349 us; speedup vs baseline: 1.1586x; 1.1586x over previous
//
#include <hip/hip_runtime.h>
#include <hip/hip_bf16.h>

// ---------------------------------------------------------------------------
// DRRGHead, 7 dispatches.
//   relu(cat(x_norm, A@x_norm) @ W + b) == relu(x@W' + b' + A@(x@W'_bot))
// BN folded into W1. GEMM+agg fused per layer: M-tile = 3 graphs (123 rows
// pad 128), Bt rows permuted so each 128-col tile = 64 L-cols + 64 R-cols;
// P stays in LDS; y = relu(P_L + A@P_R) written directly.
// R16: conv restored to TRAILING tail (R15 interleave destroyed supergroup
//   locality: L1 100->154us). Kept from R15: per-graph adjacency staging
//   (7.2KB @ 32768) -> LDS 39,984 B -> 4 blocks/CU (R15 evidence: L2/L3 with
//   only this change improved).
// GEMM core: 128x128, 2-ph dbuf global_load_lds, conflict-free slot-swizzle,
// supergroup swizzle.
// ---------------------------------------------------------------------------

using f32x4 = __attribute__((ext_vector_type(4))) float;
using s16x8 = __attribute__((ext_vector_type(8))) short;   // 8 bf16

#define GN 20992          // G*N rows
#define NFEAT 576
#define NGRAPH 512
#define NNODE 41
#define ASTR 44           // padded A row stride (44 f32 = 176 B, 16B-aligned)
#define NTMG 171          // m-tiles of 3 graphs (123 rows); 171*3 = 513 >= 512

typedef __attribute__((address_space(1))) const unsigned int gas_u32;
typedef __attribute__((address_space(3))) unsigned int las_u32;

__device__ __forceinline__ void gl_lds16(const void* g, void* l) {
  __builtin_amdgcn_global_load_lds((gas_u32*)g, (las_u32*)l, 16, 0, 0);
}

// dot over 41: A row (LDS, 16B-aligned, broadcast) . pr[] (regs), float4 reads
__device__ __forceinline__ float dot41_f4(const float* __restrict__ Am,
                                          const float* __restrict__ pr) {
  float s0 = 0.f, s1 = 0.f, s2 = 0.f, s3 = 0.f;
#pragma unroll
  for (int q = 0; q < 10; ++q) {
    float4 a4 = *(const float4*)(Am + q * 4);
    s0 += a4.x * pr[q * 4];
    s1 += a4.y * pr[q * 4 + 1];
    s2 += a4.z * pr[q * 4 + 2];
    s3 += a4.w * pr[q * 4 + 3];
  }
  return ((s0 + s1) + (s2 + s3)) + Am[40] * pr[40];
}

// ---------------- K1: fused bf16-cast + bn-stats (one pass over nf) ---------
__global__ __launch_bounds__(576) void front_kernel(
    const float* __restrict__ nf, float* __restrict__ partial,
    __hip_bfloat16* __restrict__ x0) {
  int c = threadIdx.x;                  // 0..575
  int u = blockIdx.x;                   // 0..255
  int r0 = u * 82;
  const float* src = nf + (size_t)r0 * NFEAT + c;
  __hip_bfloat16* dst = x0 + (size_t)r0 * NFEAT + c;
  float s = 0.f, s2 = 0.f;
#pragma unroll 4
  for (int r = 0; r < 82; ++r) {
    float v = src[(size_t)r * NFEAT];
    s += v; s2 += v * v;
    dst[(size_t)r * NFEAT] = __float2bfloat16(v);
  }
  partial[(size_t)u * 1152 + c] = s;
  partial[(size_t)u * 1152 + NFEAT + c] = s2;
}

// ---------------- K2: wide BN reduce -> statsbuf = {inv[576], m*inv[576]} ---
__global__ __launch_bounds__(256) void reduce_kernel(
    const float* __restrict__ partial, float* __restrict__ statsbuf) {
  int t = blockIdx.x * 256 + threadIdx.x;
  if (t >= NFEAT) return;
  float s = 0.f, s2 = 0.f;
#pragma unroll 8
  for (int u = 0; u < 256; ++u) {
    s += partial[(size_t)u * 1152 + t];
    s2 += partial[(size_t)u * 1152 + NFEAT + t];
  }
  float m = s * (1.f / GN);
  float v = s2 * (1.f / GN) - m * m;
  float inv = rsqrtf(v + 1e-5f);
  statsbuf[t] = inv;
  statsbuf[NFEAT + t] = m * inv;
}

// ---------------- K3: W1 fold-repack + cvec GEMV + W2-4 repack --------------
// All Bt writes use paired-col permutation jp = (rowh>>6)*128 + h*64 + (rowh&63)
__global__ __launch_bounds__(256) void wt1_kernel(
    const float* __restrict__ W1, const float* __restrict__ b1,
    const float* __restrict__ statsbuf, __hip_bfloat16* __restrict__ B1,
    float* __restrict__ gbias,
    const float* __restrict__ W2, const float* __restrict__ W3,
    const float* __restrict__ W4,
    __hip_bfloat16* __restrict__ B2, __hip_bfloat16* __restrict__ B3,
    __hip_bfloat16* __restrict__ B4) {
  int u = blockIdx.x;
  int tid = threadIdx.x;
  if (u < 576) {                        // fold-repack tile of W1 (2N=1024,K=576)
    __shared__ float T[32 * 33];
    int jt = u / 18, kt = u - jt * 18;
    int j0 = jt * 32, k0 = kt * 32;
    int h = (j0 >= 512) ? 1 : 0;
    const float* Wh = W1 + (size_t)(h * 576) * 512 + (j0 - h * 512);
    int r = tid >> 5, cc = tid & 31;
#pragma unroll
    for (int i = 0; i < 4; ++i)
      T[(r + i * 8) * 33 + cc] = Wh[(size_t)(k0 + r + i * 8) * 512 + cc];
    __syncthreads();
    float invv = statsbuf[k0 + cc];
#pragma unroll
    for (int i = 0; i < 4; ++i) {
      int rowh = (j0 - h * 512) + r + i * 8;
      int jp = (rowh >> 6) * 128 + h * 64 + (rowh & 63);
      B1[(size_t)jp * 576 + k0 + cc] =
          __float2bfloat16(T[cc * 33 + (r + i * 8)] * invv);
    }
  } else if (u < 580) {                 // cvec GEMV (gbias in ORIGINAL order)
    int j = (u - 576) * 256 + tid;      // 0..1023
    int col = (j < 512) ? j : j - 512;
    const float* base = W1 + (size_t)((j < 512) ? 0 : 576) * 512 + col;
    float s = 0.f;
#pragma unroll 4
    for (int f = 0; f < NFEAT; ++f) s += statsbuf[NFEAT + f] * base[(size_t)f * 512];
    gbias[j] = ((j < 512) ? b1[j] : 0.f) - s;
  } else {                              // plain repack W2/W3/W4 (permuted rows)
    __shared__ float T[32 * 33];
    int t = u - 580;
    const float* W; __hip_bfloat16* B; int K, N;
    if (t < 256)      { W = W2; B = B2; K = 512; N = 256; }
    else if (t < 320) { W = W3; B = B3; K = 256; N = 128; t -= 256; }
    else              { W = W4; B = B4; K = 128; N = 64;  t -= 320; }
    int tilesN = N >> 5;
    int perhalf = (K >> 5) * tilesN;
    int h = t / perhalf; t -= h * perhalf;
    int tk = t / tilesN, tn = t - tk * tilesN;
    int r = tid >> 5, cc = tid & 31;
    const float* Wh = W + (size_t)h * K * N;
#pragma unroll
    for (int i = 0; i < 4; ++i)
      T[(r + i * 8) * 33 + cc] = Wh[(size_t)(tk * 32 + r + i * 8) * N + tn * 32 + cc];
    __syncthreads();
#pragma unroll
    for (int i = 0; i < 4; ++i) {
      int row = tn * 32 + r + i * 8;
      int jp = (row >> 6) * 128 + h * 64 + (row & 63);
      B[(size_t)jp * K + tk * 32 + cc] =
          __float2bfloat16(T[cc * 33 + r + i * 8]);
    }
  }
}

// ---------------- fused GEMM + agg: y = relu(P_L + A@P_R), layers 1-3 -------
// M-tile = 3 graphs (123 rows pad 128); N-tile = 64 L-cols + 64 paired R-cols.
// P in LDS rows 0..127 overlay staging; Aash (one graph, 7.2KB) at [32768,
// 39984). Conv pool TRAILS the GEMM grid (L1 only).
__global__ __launch_bounds__(256) void gemmagg_kernel(
    const __hip_bfloat16* __restrict__ Xptr, const __hip_bfloat16* __restrict__ Bt,
    const float* __restrict__ biasL, const float* __restrict__ biasR,
    __hip_bfloat16* __restrict__ Yptr, int Nout, int K, int NTN,
    const float* __restrict__ Aadj,
    const float* __restrict__ cinputs, const float* __restrict__ conv_w,
    const float* __restrict__ conv_b, float* __restrict__ cout) {
  // LDS map: [0,32768) staging dbuf / Psh overlay; Aash at [32768, 39984).
  __shared__ __align__(16) char smem[39984];
  short* AshD = (short*)smem;                 // [2][128*32]
  short* BshD = (short*)(smem + 16384);       // [2][128*32]
  __hip_bfloat16* Psh = (__hip_bfloat16*)smem;
  float* Aash = (float*)(smem + 32768);

  int tid = threadIdx.x;
  int bid = blockIdx.x;
  int gemmBlocks = NTMG * NTN;

  if (bid >= gemmBlocks) {              // ---- conv pool (trailing tail, L1)
    int p = (bid - gemmBlocks) * 256 + tid;
    int img = p >> 16, q = p & 65535;
    const float4* ip = (const float4*)cinputs + (size_t)img * 32 * 65536 + q;
    float4 acc[6];
#pragma unroll
    for (int o = 0; o < 6; ++o) { float b0 = conv_b[o]; acc[o] = make_float4(b0, b0, b0, b0); }
#pragma unroll 4
    for (int c = 0; c < 32; ++c) {
      float4 x = ip[(size_t)c * 65536];
#pragma unroll
      for (int o = 0; o < 6; ++o) {
        float wv = conv_w[o * 32 + c];
        acc[o].x += x.x * wv; acc[o].y += x.y * wv;
        acc[o].z += x.z * wv; acc[o].w += x.w * wv;
      }
    }
    float4* op = (float4*)cout + (size_t)img * 6 * 65536 + q;
#pragma unroll
    for (int o = 0; o < 6; ++o) op[(size_t)o * 65536] = acc[o];
    return;
  }

  int sg = bid / (NTN * 8);
  int rem = bid - sg * (NTN * 8);
  int Wm = NTMG - sg * 8; if (Wm > 8) Wm = 8;
  int mt = sg * 8 + rem % Wm;
  int nt = rem / Wm;
  int row0 = mt * 123;
  int g0 = mt * 3;
  int gcnt = NGRAPH - g0; if (gcnt > 3) gcnt = 3;

  int wave = tid >> 6, lane = tid & 63;
  int wm = wave >> 1, wn = wave & 1;
  int lr = lane & 15, kb = lane >> 4;

  f32x4 acc[4][4];
#pragma unroll
  for (int m = 0; m < 4; ++m)
#pragma unroll
    for (int n = 0; n < 4; ++n) acc[m][n] = (f32x4){0.f, 0.f, 0.f, 0.f};

  const short* Ag = (const short*)Xptr;
  const short* Bg = (const short*)Bt + (size_t)nt * 128 * K;

  // staging: slot c holds global chunk (row = c>>2, k-chunk = (c&3)^((row>>1)&3))
  int c0 = tid, c1 = tid + 256;
  int ar0 = c0 >> 2, ak0 = (((c0 & 3) ^ ((ar0 >> 1) & 3))) * 8;
  int ar1 = c1 >> 2, ak1 = (((c1 & 3) ^ ((ar1 >> 1) & 3))) * 8;
  int grow0 = row0 + ar0; if (grow0 > GN - 1) grow0 = GN - 1;   // pad rows clamp
  int grow1 = row0 + ar1; if (grow1 > GN - 1) grow1 = GN - 1;

  // fragment read offsets (shorts): row*32 + (((row>>1)&3)^kb)*8
  int aoff[4], boff[4];
#pragma unroll
  for (int m = 0; m < 4; ++m) {
    int r = wm * 64 + m * 16 + lr;
    aoff[m] = r * 32 + ((((r >> 1) & 3) ^ kb) * 8);
  }
#pragma unroll
  for (int n = 0; n < 4; ++n) {
    int r = wn * 64 + n * 16 + lr;
    boff[n] = r * 32 + ((((r >> 1) & 3) ^ kb) * 8);
  }

  gl_lds16(Ag + (size_t)grow0 * K + ak0, &AshD[c0 * 8]);
  gl_lds16(Ag + (size_t)grow1 * K + ak1, &AshD[c1 * 8]);
  gl_lds16(Bg + (size_t)ar0 * K + ak0, &BshD[c0 * 8]);
  gl_lds16(Bg + (size_t)ar1 * K + ak1, &BshD[c1 * 8]);
  __syncthreads();

  int nkt = K >> 5;
  int cur = 0;
  for (int kt = 0; kt < nkt; ++kt) {
    if (kt + 1 < nkt) {
      int k1 = (kt + 1) * 32;
      int nxt = (cur ^ 1) * 4096;
      gl_lds16(Ag + (size_t)grow0 * K + k1 + ak0, &AshD[nxt + c0 * 8]);
      gl_lds16(Ag + (size_t)grow1 * K + k1 + ak1, &AshD[nxt + c1 * 8]);
      gl_lds16(Bg + (size_t)ar0 * K + k1 + ak0, &BshD[nxt + c0 * 8]);
      gl_lds16(Bg + (size_t)ar1 * K + k1 + ak1, &BshD[nxt + c1 * 8]);
    }
    int cb = cur * 4096;
    s16x8 af[4], bfr[4];
#pragma unroll
    for (int m = 0; m < 4; ++m) af[m] = *(const s16x8*)&AshD[cb + aoff[m]];
#pragma unroll
    for (int n = 0; n < 4; ++n) bfr[n] = *(const s16x8*)&BshD[cb + boff[n]];
#pragma unroll
    for (int m = 0; m < 4; ++m)
#pragma unroll
      for (int n = 0; n < 4; ++n)
        acc[m][n] = __builtin_amdgcn_mfma_f32_16x16x32_bf16(af[m], bfr[n], acc[m][n], 0, 0, 0);
    __syncthreads();
    cur ^= 1;
  }

  // epilogue 1: P (+bias, both halves) -> Psh overlay (safe: loop ended w/ barrier)
  int rbase = (lane >> 4) * 4;
#pragma unroll
  for (int m = 0; m < 4; ++m) {
    int lrow = wm * 64 + m * 16 + rbase;
#pragma unroll
    for (int n = 0; n < 4; ++n) {
      int w = wn * 64 + n * 16 + lr;
      float bv = (w < 64) ? biasL[nt * 64 + w]
                          : (biasR ? biasR[nt * 64 + (w - 64)] : 0.f);
#pragma unroll
      for (int r = 0; r < 4; ++r)
        Psh[(size_t)(lrow + r) * 128 + w] = __float2bfloat16(acc[m][n][r] + bv);
    }
  }
  // stage A for graph 0 (Aash disjoint from Psh -> one barrier covers both)
  {
    const float* Asrc = Aadj + (size_t)g0 * (NNODE * NNODE);
    for (int i = tid; i < NNODE * NNODE; i += 256) {
      int row = i / NNODE, m = i - row * NNODE;
      Aash[row * ASTR + m] = Asrc[i];
    }
  }
  __syncthreads();

  // epilogue 2: per graph: y[g][n][c] = relu(P_L[n][c] + dot(A[n,:], P_R[:,c]))
  int c = tid & 63, grp = tid >> 6;
  for (int g = 0; g < gcnt; ++g) {
    float pr[NNODE];
#pragma unroll
    for (int m = 0; m < NNODE; ++m)
      pr[m] = __bfloat162float(Psh[(size_t)(g * NNODE + m) * 128 + 64 + c]);
#pragma unroll 1
    for (int n = grp; n < NNODE; n += 4) {
      float aa = __bfloat162float(Psh[(size_t)(g * NNODE + n) * 128 + c])
               + dot41_f4(Aash + n * ASTR, pr);
      aa = aa > 0.f ? aa : 0.f;
      Yptr[(size_t)(row0 + g * NNODE + n) * Nout + nt * 64 + c] = __float2bfloat16(aa);
    }
    if (g + 1 < gcnt) {                 // swap Aash to next graph
      __syncthreads();                  // all reads of A_g done
      const float* Asrc = Aadj + (size_t)(g0 + g + 1) * (NNODE * NNODE);
      for (int i = tid; i < NNODE * NNODE; i += 256) {
        int row = i / NNODE, m = i - row * NNODE;
        Aash[row * ASTR + m] = Asrc[i];
      }
      __syncthreads();                  // A_{g+1} visible
    }
  }
}

// ---------------- G4F: gemm4 + agg4 + knn classifier, 3 graphs/block --------
__global__ __launch_bounds__(256) void gemm4cls_kernel(
    const __hip_bfloat16* __restrict__ X, const __hip_bfloat16* __restrict__ B4t,
    const float* __restrict__ b4, const float* __restrict__ Aadj,
    const int* __restrict__ knn, const float* __restrict__ w1,
    const float* __restrict__ cb1, const float* __restrict__ pa,
    const float* __restrict__ w2, const float* __restrict__ cb2,
    float* __restrict__ out) {
  __shared__ __align__(16) char smem[49152 + 21648 + 31488 + 8192 + 520];
  short* AshD = (short*)smem;
  short* Bsh  = (short*)(smem + 16384);
  __hip_bfloat16* Psh = (__hip_bfloat16*)smem;
  float* Aash = (float*)(smem + 49152);                   // 123 x 44 f32 padded
  float* Ysh  = (float*)(smem + 49152 + 21648);
  float* Wsh  = (float*)(smem + 49152 + 21648 + 31488);
  float* cb   = (float*)(smem + 49152 + 21648 + 31488 + 8192);

  int tid = threadIdx.x;
  int blk = blockIdx.x;
  int g0 = blk * 3;
  int gcnt = NGRAPH - g0; if (gcnt > 3) gcnt = 3;
  int row0 = blk * 123;

  {
    int tot = gcnt * (NNODE * NNODE);
    const float* Asrc = Aadj + (size_t)g0 * (NNODE * NNODE);
    for (int i = tid; i < tot; i += 256) {
      int row = i / NNODE, m = i - row * NNODE;
      Aash[row * ASTR + m] = Asrc[i];
    }
  }
  for (int i = tid; i < 2048; i += 256) Wsh[i] = w1[i];
  if (tid < 32) { cb[tid] = cb1[tid]; cb[32 + tid] = pa[tid]; }
  if (tid < 64) cb[64 + tid] = w2[tid];
  if (tid < 2) cb[128 + tid] = cb2[tid];

  // stage whole B4t (4 ktiles), slot-swizzled within each ktile
#pragma unroll
  for (int i = 0; i < 8; ++i) {
    int c = tid + i * 256;              // 2048 chunks of 16B
    int kt = c >> 9, w = c & 511;
    int r = w >> 2, kc = ((w & 3) ^ ((r >> 1) & 3)) * 8;
    gl_lds16((const short*)B4t + (size_t)r * 128 + kt * 32 + kc, &Bsh[c * 8]);
  }
  // stage A k-tile 0 (swizzled)
  const short* Ag = (const short*)X;
  int c0 = tid, c1 = tid + 256;
  int ar0 = c0 >> 2, ak0 = (((c0 & 3) ^ ((ar0 >> 1) & 3))) * 8;
  int ar1 = c1 >> 2, ak1 = (((c1 & 3) ^ ((ar1 >> 1) & 3))) * 8;
  int grow0 = row0 + ar0; if (grow0 > GN - 1) grow0 = GN - 1;
  int grow1 = row0 + ar1; if (grow1 > GN - 1) grow1 = GN - 1;
  gl_lds16(Ag + (size_t)grow0 * 128 + ak0, &AshD[c0 * 8]);
  gl_lds16(Ag + (size_t)grow1 * 128 + ak1, &AshD[c1 * 8]);
  __syncthreads();

  int wave = tid >> 6, lane = tid & 63;
  int wm = wave >> 1, wn = wave & 1;
  int lr = lane & 15, kb = lane >> 4;
  int aoff[4], boff[4];
#pragma unroll
  for (int m = 0; m < 4; ++m) {
    int r = wm * 64 + m * 16 + lr;
    aoff[m] = r * 32 + ((((r >> 1) & 3) ^ kb) * 8);
  }
#pragma unroll
  for (int n = 0; n < 4; ++n) {
    int r = wn * 64 + n * 16 + lr;
    boff[n] = r * 32 + ((((r >> 1) & 3) ^ kb) * 8);
  }
  f32x4 acc[4][4];
#pragma unroll
  for (int m = 0; m < 4; ++m)
#pragma unroll
    for (int n = 0; n < 4; ++n) acc[m][n] = (f32x4){0.f, 0.f, 0.f, 0.f};

  int cur = 0;
  for (int kt = 0; kt < 4; ++kt) {
    if (kt < 3) {
      int k1 = (kt + 1) * 32;
      int nxt = (cur ^ 1) * 4096;
      gl_lds16(Ag + (size_t)grow0 * 128 + k1 + ak0, &AshD[nxt + c0 * 8]);
      gl_lds16(Ag + (size_t)grow1 * 128 + k1 + ak1, &AshD[nxt + c1 * 8]);
    }
    int cbse = cur * 4096;
    s16x8 af[4], bfr[4];
#pragma unroll
    for (int m = 0; m < 4; ++m) af[m] = *(const s16x8*)&AshD[cbse + aoff[m]];
#pragma unroll
    for (int n = 0; n < 4; ++n) bfr[n] = *(const s16x8*)&Bsh[kt * 4096 + boff[n]];
#pragma unroll
    for (int m = 0; m < 4; ++m)
#pragma unroll
      for (int n = 0; n < 4; ++n)
        acc[m][n] = __builtin_amdgcn_mfma_f32_16x16x32_bf16(af[m], bfr[n], acc[m][n], 0, 0, 0);
    __syncthreads();
    cur ^= 1;
  }
  // epilogue -> Psh
  int rbase = (lane >> 4) * 4;
#pragma unroll
  for (int m = 0; m < 4; ++m) {
    int lrow = wm * 64 + m * 16 + rbase;
#pragma unroll
    for (int n = 0; n < 4; ++n) {
      int col = wn * 64 + n * 16 + lr;
      float bv = (col < 64) ? b4[col] : 0.f;
#pragma unroll
      for (int r = 0; r < 4; ++r)
        Psh[(size_t)(lrow + r) * 128 + col] = __float2bfloat16(acc[m][n][r] + bv);
    }
  }
  __syncthreads();

  // agg into Ysh (float4 broadcast dot)
  int c = tid & 63, grp = tid >> 6;
  for (int g = 0; g < gcnt; ++g) {
    float pr[NNODE];
#pragma unroll
    for (int m = 0; m < NNODE; ++m)
      pr[m] = __bfloat162float(Psh[(size_t)(g * NNODE + m) * 128 + 64 + c]);
#pragma unroll 1
    for (int n = grp; n < NNODE; n += 4) {
      float aa = __bfloat162float(Psh[(size_t)(g * NNODE + n) * 128 + c])
               + dot41_f4(Aash + (g * NNODE + n) * ASTR, pr);
      Ysh[(g * NNODE + n) * 64 + c] = aa > 0.f ? aa : 0.f;
    }
  }
  __syncthreads();

  // classifier: 8*gcnt edges, 32 lanes each
  int j = tid & 31, slot = tid >> 5;
  for (int el = slot; el < 8 * gcnt; el += 8) {
    int e = g0 * 8 + el;
    int node = knn[e];
    int gl = el >> 3;
    const float* fp = &Ysh[(gl * NNODE + node) * 64];
    float a2 = cb[j];
#pragma unroll
    for (int d = 0; d < 64; ++d) a2 += fp[d] * Wsh[d * 32 + j];
    float h = a2 >= 0.f ? a2 : cb[32 + j] * a2;
#pragma unroll
    for (int o = 0; o < 2; ++o) {
      float v = h * cb[64 + j * 2 + o];
      v += __shfl_xor(v, 16, 32); v += __shfl_xor(v, 8, 32);
      v += __shfl_xor(v, 4, 32);  v += __shfl_xor(v, 2, 32);
      v += __shfl_xor(v, 1, 32);
      if (j == 0) out[(size_t)e * 2 + o] = v;
    }
  }
}

// ---------------------------------------------------------------------------
extern "C" void kernel_launch(void* const* d_in, const int* in_sizes, int n_in,
                              void* d_out, int out_size, void* d_ws, size_t ws_size,
                              hipStream_t stream) {
  const float* inputs     = (const float*)d_in[0];
  const float* node_feats = (const float*)d_in[1];
  const float* Aadj       = (const float*)d_in[2];
  const int*   knn        = (const int*)d_in[3];
  const float* conv_w     = (const float*)d_in[4];
  const float* conv_b     = (const float*)d_in[5];
  const float* W1 = (const float*)d_in[6];  const float* b1 = (const float*)d_in[7];
  const float* W2 = (const float*)d_in[8];  const float* b2 = (const float*)d_in[9];
  const float* W3 = (const float*)d_in[10]; const float* b3 = (const float*)d_in[11];
  const float* W4 = (const float*)d_in[12]; const float* b4 = (const float*)d_in[13];
  const float* cls_w1 = (const float*)d_in[14]; const float* cls_b1 = (const float*)d_in[15];
  const float* prelu_a = (const float*)d_in[16];
  const float* cls_w2 = (const float*)d_in[17]; const float* cls_b2 = (const float*)d_in[18];
  float* out = (float*)d_out;

  char* ws = (char*)d_ws;
  char* R1 = ws;                        // x0 (24.2 MB) -> y2 (10.7 MB)
  char* R2 = ws + 24200192;             // y1 (21.5 MB) -> y3 (5.4 MB)
  char* wp = ws + 24200192 + 42991616;
  __hip_bfloat16* B1t = (__hip_bfloat16*)wp;  wp += 1179648;   // 1024 x 576
  __hip_bfloat16* B2t = (__hip_bfloat16*)wp;  wp += 524288;    // 512 x 512
  __hip_bfloat16* B3t = (__hip_bfloat16*)wp;  wp += 131072;    // 256 x 256
  __hip_bfloat16* B4t = (__hip_bfloat16*)wp;  wp += 32768;     // 128 x 128
  float* partial  = (float*)wp;               wp += 256 * 1152 * 4;
  float* statsbuf = (float*)wp;               wp += 1152 * 4;
  float* gbias    = (float*)wp;               wp += 1024 * 4;

  __hip_bfloat16* x0 = (__hip_bfloat16*)R1;

  // K1: fused cast + stats (one pass over node_feats)
  front_kernel<<<256, 576, 0, stream>>>(node_feats, partial, x0);
  // K2: wide BN reduce
  reduce_kernel<<<3, 256, 0, stream>>>(partial, statsbuf);
  // K3: W1 fold-repack + cvec GEMV + W2-4 repack (paired-col permutation)
  wt1_kernel<<<932, 256, 0, stream>>>(W1, b1, statsbuf, B1t, gbias,
                                      W2, W3, W4, B2t, B3t, B4t);

  // L1 fused gemm+agg (+ trailing conv tail): x0 -> y1 (R2), Nout=512, K=576
  gemmagg_kernel<<<NTMG * 8 + 1024, 256, 0, stream>>>(
      x0, B1t, gbias, gbias + 512, (__hip_bfloat16*)R2, 512, 576, 8,
      Aadj, inputs, conv_w, conv_b, out);
  // L2: y1 -> y2 (R1), Nout=256, K=512, NTN=4
  gemmagg_kernel<<<NTMG * 4, 256, 0, stream>>>(
      (__hip_bfloat16*)R2, B2t, b2, nullptr, (__hip_bfloat16*)R1, 256, 512, 4,
      Aadj, nullptr, nullptr, nullptr, nullptr);
  // L3: y2 -> y3 (R2), Nout=128, K=256, NTN=2
  gemmagg_kernel<<<NTMG * 2, 256, 0, stream>>>(
      (__hip_bfloat16*)R1, B3t, b3, nullptr, (__hip_bfloat16*)R2, 128, 256, 2,
      Aadj, nullptr, nullptr, nullptr, nullptr);
  // L4 fused: gemm + agg + knn classifier
  gemm4cls_kernel<<<171, 256, 0, stream>>>(
      (__hip_bfloat16*)R2, B4t, b4, Aadj, knn, cls_w1, cls_b1, prelu_a,
      cls_w2, cls_b2, out + 6291456);
}

// Round 17
// 244.609 us; speedup vs baseline: 1.1716x; 1.0112x over previous
//
#include <hip/hip_runtime.h>
#include <hip/hip_bf16.h>

// ---------------------------------------------------------------------------
// DRRGHead, 7 dispatches.
//   relu(cat(x_norm, A@x_norm) @ W + b) == relu(x@W' + b' + A@(x@W'_bot))
// BN folded into W1. GEMM+agg fused per layer; Bt rows permuted so each
// 128-row weight tile = 64 L-cols + their 64 R-cols; P stays in LDS.
// R17: L1 uses a 512-thread 8-wave 256x128-tile variant (6-graph M-tiles):
//   3 gl_lds16/thread (was 4), half the blocks/barriers, 16 waves/CU
//   (2 blocks x 8 waves), 8-way epilogue n-parallelism. L2/L3 keep the
//   R14 256-thread kernel (best measured). Conv trails L1's grid.
// GEMM core: 2-ph dbuf global_load_lds, conflict-free slot-swizzle,
// supergroup swizzle.
// ---------------------------------------------------------------------------

using f32x4 = __attribute__((ext_vector_type(4))) float;
using s16x8 = __attribute__((ext_vector_type(8))) short;   // 8 bf16

#define GN 20992          // G*N rows
#define NFEAT 576
#define NGRAPH 512
#define NNODE 41
#define ASTR 44           // padded A row stride (44 f32 = 176 B, 16B-aligned)
#define NTMG 171          // 3-graph m-tiles (123 rows); 171*3 = 513 >= 512
#define NTMG6 86          // 6-graph m-tiles (246 rows); 86*6 = 516 >= 512

typedef __attribute__((address_space(1))) const unsigned int gas_u32;
typedef __attribute__((address_space(3))) unsigned int las_u32;

__device__ __forceinline__ void gl_lds16(const void* g, void* l) {
  __builtin_amdgcn_global_load_lds((gas_u32*)g, (las_u32*)l, 16, 0, 0);
}

// dot over 41: A row (LDS, 16B-aligned, broadcast) . pr[] (regs), float4 reads
__device__ __forceinline__ float dot41_f4(const float* __restrict__ Am,
                                          const float* __restrict__ pr) {
  float s0 = 0.f, s1 = 0.f, s2 = 0.f, s3 = 0.f;
#pragma unroll
  for (int q = 0; q < 10; ++q) {
    float4 a4 = *(const float4*)(Am + q * 4);
    s0 += a4.x * pr[q * 4];
    s1 += a4.y * pr[q * 4 + 1];
    s2 += a4.z * pr[q * 4 + 2];
    s3 += a4.w * pr[q * 4 + 3];
  }
  return ((s0 + s1) + (s2 + s3)) + Am[40] * pr[40];
}

// ---------------- K1: fused bf16-cast + bn-stats (one pass over nf) ---------
__global__ __launch_bounds__(576) void front_kernel(
    const float* __restrict__ nf, float* __restrict__ partial,
    __hip_bfloat16* __restrict__ x0) {
  int c = threadIdx.x;                  // 0..575
  int u = blockIdx.x;                   // 0..255
  int r0 = u * 82;
  const float* src = nf + (size_t)r0 * NFEAT + c;
  __hip_bfloat16* dst = x0 + (size_t)r0 * NFEAT + c;
  float s = 0.f, s2 = 0.f;
#pragma unroll 4
  for (int r = 0; r < 82; ++r) {
    float v = src[(size_t)r * NFEAT];
    s += v; s2 += v * v;
    dst[(size_t)r * NFEAT] = __float2bfloat16(v);
  }
  partial[(size_t)u * 1152 + c] = s;
  partial[(size_t)u * 1152 + NFEAT + c] = s2;
}

// ---------------- K2: wide BN reduce -> statsbuf = {inv[576], m*inv[576]} ---
__global__ __launch_bounds__(256) void reduce_kernel(
    const float* __restrict__ partial, float* __restrict__ statsbuf) {
  int t = blockIdx.x * 256 + threadIdx.x;
  if (t >= NFEAT) return;
  float s = 0.f, s2 = 0.f;
#pragma unroll 8
  for (int u = 0; u < 256; ++u) {
    s += partial[(size_t)u * 1152 + t];
    s2 += partial[(size_t)u * 1152 + NFEAT + t];
  }
  float m = s * (1.f / GN);
  float v = s2 * (1.f / GN) - m * m;
  float inv = rsqrtf(v + 1e-5f);
  statsbuf[t] = inv;
  statsbuf[NFEAT + t] = m * inv;
}

// ---------------- K3: W1 fold-repack + cvec GEMV + W2-4 repack --------------
// All Bt writes use paired-col permutation jp = (rowh>>6)*128 + h*64 + (rowh&63)
__global__ __launch_bounds__(256) void wt1_kernel(
    const float* __restrict__ W1, const float* __restrict__ b1,
    const float* __restrict__ statsbuf, __hip_bfloat16* __restrict__ B1,
    float* __restrict__ gbias,
    const float* __restrict__ W2, const float* __restrict__ W3,
    const float* __restrict__ W4,
    __hip_bfloat16* __restrict__ B2, __hip_bfloat16* __restrict__ B3,
    __hip_bfloat16* __restrict__ B4) {
  int u = blockIdx.x;
  int tid = threadIdx.x;
  if (u < 576) {                        // fold-repack tile of W1 (2N=1024,K=576)
    __shared__ float T[32 * 33];
    int jt = u / 18, kt = u - jt * 18;
    int j0 = jt * 32, k0 = kt * 32;
    int h = (j0 >= 512) ? 1 : 0;
    const float* Wh = W1 + (size_t)(h * 576) * 512 + (j0 - h * 512);
    int r = tid >> 5, cc = tid & 31;
#pragma unroll
    for (int i = 0; i < 4; ++i)
      T[(r + i * 8) * 33 + cc] = Wh[(size_t)(k0 + r + i * 8) * 512 + cc];
    __syncthreads();
    float invv = statsbuf[k0 + cc];
#pragma unroll
    for (int i = 0; i < 4; ++i) {
      int rowh = (j0 - h * 512) + r + i * 8;
      int jp = (rowh >> 6) * 128 + h * 64 + (rowh & 63);
      B1[(size_t)jp * 576 + k0 + cc] =
          __float2bfloat16(T[cc * 33 + (r + i * 8)] * invv);
    }
  } else if (u < 580) {                 // cvec GEMV (gbias in ORIGINAL order)
    int j = (u - 576) * 256 + tid;      // 0..1023
    int col = (j < 512) ? j : j - 512;
    const float* base = W1 + (size_t)((j < 512) ? 0 : 576) * 512 + col;
    float s = 0.f;
#pragma unroll 4
    for (int f = 0; f < NFEAT; ++f) s += statsbuf[NFEAT + f] * base[(size_t)f * 512];
    gbias[j] = ((j < 512) ? b1[j] : 0.f) - s;
  } else {                              // plain repack W2/W3/W4 (permuted rows)
    __shared__ float T[32 * 33];
    int t = u - 580;
    const float* W; __hip_bfloat16* B; int K, N;
    if (t < 256)      { W = W2; B = B2; K = 512; N = 256; }
    else if (t < 320) { W = W3; B = B3; K = 256; N = 128; t -= 256; }
    else              { W = W4; B = B4; K = 128; N = 64;  t -= 320; }
    int tilesN = N >> 5;
    int perhalf = (K >> 5) * tilesN;
    int h = t / perhalf; t -= h * perhalf;
    int tk = t / tilesN, tn = t - tk * tilesN;
    int r = tid >> 5, cc = tid & 31;
    const float* Wh = W + (size_t)h * K * N;
#pragma unroll
    for (int i = 0; i < 4; ++i)
      T[(r + i * 8) * 33 + cc] = Wh[(size_t)(tk * 32 + r + i * 8) * N + tn * 32 + cc];
    __syncthreads();
#pragma unroll
    for (int i = 0; i < 4; ++i) {
      int row = tn * 32 + r + i * 8;
      int jp = (row >> 6) * 128 + h * 64 + (row & 63);
      B[(size_t)jp * K + tk * 32 + cc] =
          __float2bfloat16(T[cc * 33 + r + i * 8]);
    }
  }
}

// ---------------- L1: 512-thread fused GEMM+agg, 256x128 tile ---------------
// 8 waves (4m x 2n), per-wave 64x64; M-tile = 6 graphs (246 rows pad 256).
// LDS: A dbuf 32KB + B dbuf 16KB = 48KB staging; Psh 256x128 bf16 (64KB)
// overlays; Aash (2 graphs, 14.4KB) at 65536. Total 79968 -> 2 blocks/CU.
// Conv pool trails the GEMM grid.
__global__ __launch_bounds__(512) void gemmagg512_kernel(
    const __hip_bfloat16* __restrict__ Xptr, const __hip_bfloat16* __restrict__ Bt,
    const float* __restrict__ biasL, const float* __restrict__ biasR,
    __hip_bfloat16* __restrict__ Yptr, int Nout, int K, int NTN,
    const float* __restrict__ Aadj,
    const float* __restrict__ cinputs, const float* __restrict__ conv_w,
    const float* __restrict__ conv_b, float* __restrict__ cout) {
  __shared__ __align__(16) char smem[79968];
  short* AshD = (short*)smem;                 // [2][256*32] (8192 shorts/buf)
  short* BshD = (short*)(smem + 32768);       // [2][128*32] (4096 shorts/buf)
  __hip_bfloat16* Psh = (__hip_bfloat16*)smem;  // 256 x 128
  float* Aash = (float*)(smem + 65536);       // 2 graphs x 41 x ASTR

  int tid = threadIdx.x;
  int bid = blockIdx.x;
  int gemmBlocks = NTMG6 * NTN;

  if (bid >= gemmBlocks) {              // ---- conv pool (trailing tail)
    int p = (bid - gemmBlocks) * 512 + tid;
    int img = p >> 16, q = p & 65535;
    const float4* ip = (const float4*)cinputs + (size_t)img * 32 * 65536 + q;
    float4 acc[6];
#pragma unroll
    for (int o = 0; o < 6; ++o) { float b0 = conv_b[o]; acc[o] = make_float4(b0, b0, b0, b0); }
#pragma unroll 4
    for (int c = 0; c < 32; ++c) {
      float4 x = ip[(size_t)c * 65536];
#pragma unroll
      for (int o = 0; o < 6; ++o) {
        float wv = conv_w[o * 32 + c];
        acc[o].x += x.x * wv; acc[o].y += x.y * wv;
        acc[o].z += x.z * wv; acc[o].w += x.w * wv;
      }
    }
    float4* op = (float4*)cout + (size_t)img * 6 * 65536 + q;
#pragma unroll
    for (int o = 0; o < 6; ++o) op[(size_t)o * 65536] = acc[o];
    return;
  }

  int sg = bid / (NTN * 8);
  int rem = bid - sg * (NTN * 8);
  int Wm = NTMG6 - sg * 8; if (Wm > 8) Wm = 8;
  int mt = sg * 8 + rem % Wm;
  int nt = rem / Wm;
  int row0 = mt * 246;
  int g0 = mt * 6;
  int gcnt = NGRAPH - g0; if (gcnt > 6) gcnt = 6;

  int wave = tid >> 6, lane = tid & 63;
  int wm = wave >> 1, wn = wave & 1;    // wm 0..3, wn 0..1
  int lr = lane & 15, kb = lane >> 4;

  f32x4 acc[4][4];
#pragma unroll
  for (int m = 0; m < 4; ++m)
#pragma unroll
    for (int n = 0; n < 4; ++n) acc[m][n] = (f32x4){0.f, 0.f, 0.f, 0.f};

  const short* Ag = (const short*)Xptr;
  const short* Bg = (const short*)Bt + (size_t)nt * 128 * K;

  // A: 1024 slots (2/thread); B: 512 slots (1/thread)
  int c0 = tid, c1 = tid + 512;
  int ar0 = c0 >> 2, ak0 = (((c0 & 3) ^ ((ar0 >> 1) & 3))) * 8;
  int ar1 = c1 >> 2, ak1 = (((c1 & 3) ^ ((ar1 >> 1) & 3))) * 8;
  int grow0 = row0 + ar0; if (grow0 > GN - 1) grow0 = GN - 1;
  int grow1 = row0 + ar1; if (grow1 > GN - 1) grow1 = GN - 1;
  int br0 = c0 >> 2;                    // B uses slots 0..511: row = tid>>2
  int bk0 = (((c0 & 3) ^ ((br0 >> 1) & 3))) * 8;

  int aoff[4], boff[4];
#pragma unroll
  for (int m = 0; m < 4; ++m) {
    int r = wm * 64 + m * 16 + lr;      // 0..255
    aoff[m] = r * 32 + ((((r >> 1) & 3) ^ kb) * 8);
  }
#pragma unroll
  for (int n = 0; n < 4; ++n) {
    int r = wn * 64 + n * 16 + lr;      // 0..127
    boff[n] = r * 32 + ((((r >> 1) & 3) ^ kb) * 8);
  }

  gl_lds16(Ag + (size_t)grow0 * K + ak0, &AshD[c0 * 8]);
  gl_lds16(Ag + (size_t)grow1 * K + ak1, &AshD[c1 * 8]);
  gl_lds16(Bg + (size_t)br0 * K + bk0, &BshD[c0 * 8]);
  __syncthreads();

  int nkt = K >> 5;
  int cur = 0;
  for (int kt = 0; kt < nkt; ++kt) {
    if (kt + 1 < nkt) {
      int k1 = (kt + 1) * 32;
      int nxtA = (cur ^ 1) * 8192;
      int nxtB = (cur ^ 1) * 4096;
      gl_lds16(Ag + (size_t)grow0 * K + k1 + ak0, &AshD[nxtA + c0 * 8]);
      gl_lds16(Ag + (size_t)grow1 * K + k1 + ak1, &AshD[nxtA + c1 * 8]);
      gl_lds16(Bg + (size_t)br0 * K + k1 + bk0, &BshD[nxtB + c0 * 8]);
    }
    int cbA = cur * 8192, cbB = cur * 4096;
    s16x8 af[4], bfr[4];
#pragma unroll
    for (int m = 0; m < 4; ++m) af[m] = *(const s16x8*)&AshD[cbA + aoff[m]];
#pragma unroll
    for (int n = 0; n < 4; ++n) bfr[n] = *(const s16x8*)&BshD[cbB + boff[n]];
#pragma unroll
    for (int m = 0; m < 4; ++m)
#pragma unroll
      for (int n = 0; n < 4; ++n)
        acc[m][n] = __builtin_amdgcn_mfma_f32_16x16x32_bf16(af[m], bfr[n], acc[m][n], 0, 0, 0);
    __syncthreads();
    cur ^= 1;
  }

  // epilogue 1: P (+bias) -> Psh overlay (post-barrier, staging dead)
  int rbase = (lane >> 4) * 4;
#pragma unroll
  for (int m = 0; m < 4; ++m) {
    int lrow = wm * 64 + m * 16 + rbase;
#pragma unroll
    for (int n = 0; n < 4; ++n) {
      int w = wn * 64 + n * 16 + lr;
      float bv = (w < 64) ? biasL[nt * 64 + w] : biasR[nt * 64 + (w - 64)];
#pragma unroll
      for (int r = 0; r < 4; ++r)
        Psh[(size_t)(lrow + r) * 128 + w] = __float2bfloat16(acc[m][n][r] + bv);
    }
  }

  // epilogue 2: graphs in pairs; Aash holds 2 graphs (disjoint from Psh)
  int c = tid & 63, grp = tid >> 6;     // grp 0..7
  for (int gp = 0; gp < gcnt; gp += 2) {
    int gpe = gp + 2; if (gpe > gcnt) gpe = gcnt;
    __syncthreads();                    // P writes (1st it) / prior A reads done
    {
      int tot = (gpe - gp) * (NNODE * NNODE);
      const float* Asrc = Aadj + (size_t)(g0 + gp) * (NNODE * NNODE);
      for (int i = tid; i < tot; i += 512) {
        int row = i / NNODE, m = i - row * NNODE;
        Aash[row * ASTR + m] = Asrc[i];
      }
    }
    __syncthreads();
    for (int g = gp; g < gpe; ++g) {
      float pr[NNODE];
#pragma unroll
      for (int m = 0; m < NNODE; ++m)
        pr[m] = __bfloat162float(Psh[(size_t)(g * NNODE + m) * 128 + 64 + c]);
      const float* Am = Aash + (g - gp) * (NNODE * ASTR);
#pragma unroll 1
      for (int n = grp; n < NNODE; n += 8) {
        float aa = __bfloat162float(Psh[(size_t)(g * NNODE + n) * 128 + c])
                 + dot41_f4(Am + n * ASTR, pr);
        aa = aa > 0.f ? aa : 0.f;
        Yptr[(size_t)(row0 + g * NNODE + n) * Nout + nt * 64 + c] = __float2bfloat16(aa);
      }
    }
  }
}

// ---------------- L2/L3: 256-thread fused GEMM+agg (R14 version) ------------
__global__ __launch_bounds__(256) void gemmagg_kernel(
    const __hip_bfloat16* __restrict__ Xptr, const __hip_bfloat16* __restrict__ Bt,
    const float* __restrict__ biasL, const float* __restrict__ biasR,
    __hip_bfloat16* __restrict__ Yptr, int Nout, int K, int NTN,
    const float* __restrict__ Aadj) {
  // LDS map: [0,32768) staging dbuf; Psh rows 0..122 = [0,31488);
  //          Aash (123 x 44 f32 = 21648 B) at [31488, 53136).
  __shared__ __align__(16) char smem[53136];
  short* AshD = (short*)smem;                 // [2][128*32]
  short* BshD = (short*)(smem + 16384);       // [2][128*32]
  __hip_bfloat16* Psh = (__hip_bfloat16*)smem;
  float* Aash = (float*)(smem + 31488);

  int tid = threadIdx.x;
  int bid = blockIdx.x;

  int sg = bid / (NTN * 8);
  int rem = bid - sg * (NTN * 8);
  int Wm = NTMG - sg * 8; if (Wm > 8) Wm = 8;
  int mt = sg * 8 + rem % Wm;
  int nt = rem / Wm;
  int row0 = mt * 123;
  int g0 = mt * 3;
  int gcnt = NGRAPH - g0; if (gcnt > 3) gcnt = 3;

  int wave = tid >> 6, lane = tid & 63;
  int wm = wave >> 1, wn = wave & 1;
  int lr = lane & 15, kb = lane >> 4;

  f32x4 acc[4][4];
#pragma unroll
  for (int m = 0; m < 4; ++m)
#pragma unroll
    for (int n = 0; n < 4; ++n) acc[m][n] = (f32x4){0.f, 0.f, 0.f, 0.f};

  const short* Ag = (const short*)Xptr;
  const short* Bg = (const short*)Bt + (size_t)nt * 128 * K;

  int c0 = tid, c1 = tid + 256;
  int ar0 = c0 >> 2, ak0 = (((c0 & 3) ^ ((ar0 >> 1) & 3))) * 8;
  int ar1 = c1 >> 2, ak1 = (((c1 & 3) ^ ((ar1 >> 1) & 3))) * 8;
  int grow0 = row0 + ar0; if (grow0 > GN - 1) grow0 = GN - 1;
  int grow1 = row0 + ar1; if (grow1 > GN - 1) grow1 = GN - 1;

  int aoff[4], boff[4];
#pragma unroll
  for (int m = 0; m < 4; ++m) {
    int r = wm * 64 + m * 16 + lr;
    aoff[m] = r * 32 + ((((r >> 1) & 3) ^ kb) * 8);
  }
#pragma unroll
  for (int n = 0; n < 4; ++n) {
    int r = wn * 64 + n * 16 + lr;
    boff[n] = r * 32 + ((((r >> 1) & 3) ^ kb) * 8);
  }

  gl_lds16(Ag + (size_t)grow0 * K + ak0, &AshD[c0 * 8]);
  gl_lds16(Ag + (size_t)grow1 * K + ak1, &AshD[c1 * 8]);
  gl_lds16(Bg + (size_t)ar0 * K + ak0, &BshD[c0 * 8]);
  gl_lds16(Bg + (size_t)ar1 * K + ak1, &BshD[c1 * 8]);
  __syncthreads();

  int nkt = K >> 5;
  int cur = 0;
  for (int kt = 0; kt < nkt; ++kt) {
    if (kt + 1 < nkt) {
      int k1 = (kt + 1) * 32;
      int nxt = (cur ^ 1) * 4096;
      gl_lds16(Ag + (size_t)grow0 * K + k1 + ak0, &AshD[nxt + c0 * 8]);
      gl_lds16(Ag + (size_t)grow1 * K + k1 + ak1, &AshD[nxt + c1 * 8]);
      gl_lds16(Bg + (size_t)ar0 * K + k1 + ak0, &BshD[nxt + c0 * 8]);
      gl_lds16(Bg + (size_t)ar1 * K + k1 + ak1, &BshD[nxt + c1 * 8]);
    }
    int cb = cur * 4096;
    s16x8 af[4], bfr[4];
#pragma unroll
    for (int m = 0; m < 4; ++m) af[m] = *(const s16x8*)&AshD[cb + aoff[m]];
#pragma unroll
    for (int n = 0; n < 4; ++n) bfr[n] = *(const s16x8*)&BshD[cb + boff[n]];
#pragma unroll
    for (int m = 0; m < 4; ++m)
#pragma unroll
      for (int n = 0; n < 4; ++n)
        acc[m][n] = __builtin_amdgcn_mfma_f32_16x16x32_bf16(af[m], bfr[n], acc[m][n], 0, 0, 0);
    __syncthreads();
    cur ^= 1;
  }

  int rbase = (lane >> 4) * 4;
#pragma unroll
  for (int m = 0; m < 4; ++m) {
    int lrow = wm * 64 + m * 16 + rbase;
#pragma unroll
    for (int n = 0; n < 4; ++n) {
      int w = wn * 64 + n * 16 + lr;
      float bv = (w < 64) ? biasL[nt * 64 + w]
                          : (biasR ? biasR[nt * 64 + (w - 64)] : 0.f);
#pragma unroll
      for (int r = 0; r < 4; ++r)
        Psh[(size_t)(lrow + r) * 128 + w] = __float2bfloat16(acc[m][n][r] + bv);
    }
  }
  __syncthreads();

  {
    int tot = gcnt * (NNODE * NNODE);
    const float* Asrc = Aadj + (size_t)g0 * (NNODE * NNODE);
    for (int i = tid; i < tot; i += 256) {
      int row = i / NNODE, m = i - row * NNODE;
      Aash[row * ASTR + m] = Asrc[i];
    }
  }
  __syncthreads();

  int c = tid & 63, grp = tid >> 6;
  for (int g = 0; g < gcnt; ++g) {
    float pr[NNODE];
#pragma unroll
    for (int m = 0; m < NNODE; ++m)
      pr[m] = __bfloat162float(Psh[(size_t)(g * NNODE + m) * 128 + 64 + c]);
#pragma unroll 1
    for (int n = grp; n < NNODE; n += 4) {
      float aa = __bfloat162float(Psh[(size_t)(g * NNODE + n) * 128 + c])
               + dot41_f4(Aash + (g * NNODE + n) * ASTR, pr);
      aa = aa > 0.f ? aa : 0.f;
      Yptr[(size_t)(row0 + g * NNODE + n) * Nout + nt * 64 + c] = __float2bfloat16(aa);
    }
  }
}

// ---------------- G4F: gemm4 + agg4 + knn classifier, 3 graphs/block --------
__global__ __launch_bounds__(256) void gemm4cls_kernel(
    const __hip_bfloat16* __restrict__ X, const __hip_bfloat16* __restrict__ B4t,
    const float* __restrict__ b4, const float* __restrict__ Aadj,
    const int* __restrict__ knn, const float* __restrict__ w1,
    const float* __restrict__ cb1, const float* __restrict__ pa,
    const float* __restrict__ w2, const float* __restrict__ cb2,
    float* __restrict__ out) {
  __shared__ __align__(16) char smem[49152 + 21648 + 31488 + 8192 + 520];
  short* AshD = (short*)smem;
  short* Bsh  = (short*)(smem + 16384);
  __hip_bfloat16* Psh = (__hip_bfloat16*)smem;
  float* Aash = (float*)(smem + 49152);                   // 123 x 44 f32 padded
  float* Ysh  = (float*)(smem + 49152 + 21648);
  float* Wsh  = (float*)(smem + 49152 + 21648 + 31488);
  float* cb   = (float*)(smem + 49152 + 21648 + 31488 + 8192);

  int tid = threadIdx.x;
  int blk = blockIdx.x;
  int g0 = blk * 3;
  int gcnt = NGRAPH - g0; if (gcnt > 3) gcnt = 3;
  int row0 = blk * 123;

  {
    int tot = gcnt * (NNODE * NNODE);
    const float* Asrc = Aadj + (size_t)g0 * (NNODE * NNODE);
    for (int i = tid; i < tot; i += 256) {
      int row = i / NNODE, m = i - row * NNODE;
      Aash[row * ASTR + m] = Asrc[i];
    }
  }
  for (int i = tid; i < 2048; i += 256) Wsh[i] = w1[i];
  if (tid < 32) { cb[tid] = cb1[tid]; cb[32 + tid] = pa[tid]; }
  if (tid < 64) cb[64 + tid] = w2[tid];
  if (tid < 2) cb[128 + tid] = cb2[tid];

#pragma unroll
  for (int i = 0; i < 8; ++i) {
    int c = tid + i * 256;              // 2048 chunks of 16B
    int kt = c >> 9, w = c & 511;
    int r = w >> 2, kc = ((w & 3) ^ ((r >> 1) & 3)) * 8;
    gl_lds16((const short*)B4t + (size_t)r * 128 + kt * 32 + kc, &Bsh[c * 8]);
  }
  const short* Ag = (const short*)X;
  int c0 = tid, c1 = tid + 256;
  int ar0 = c0 >> 2, ak0 = (((c0 & 3) ^ ((ar0 >> 1) & 3))) * 8;
  int ar1 = c1 >> 2, ak1 = (((c1 & 3) ^ ((ar1 >> 1) & 3))) * 8;
  int grow0 = row0 + ar0; if (grow0 > GN - 1) grow0 = GN - 1;
  int grow1 = row0 + ar1; if (grow1 > GN - 1) grow1 = GN - 1;
  gl_lds16(Ag + (size_t)grow0 * 128 + ak0, &AshD[c0 * 8]);
  gl_lds16(Ag + (size_t)grow1 * 128 + ak1, &AshD[c1 * 8]);
  __syncthreads();

  int wave = tid >> 6, lane = tid & 63;
  int wm = wave >> 1, wn = wave & 1;
  int lr = lane & 15, kb = lane >> 4;
  int aoff[4], boff[4];
#pragma unroll
  for (int m = 0; m < 4; ++m) {
    int r = wm * 64 + m * 16 + lr;
    aoff[m] = r * 32 + ((((r >> 1) & 3) ^ kb) * 8);
  }
#pragma unroll
  for (int n = 0; n < 4; ++n) {
    int r = wn * 64 + n * 16 + lr;
    boff[n] = r * 32 + ((((r >> 1) & 3) ^ kb) * 8);
  }
  f32x4 acc[4][4];
#pragma unroll
  for (int m = 0; m < 4; ++m)
#pragma unroll
    for (int n = 0; n < 4; ++n) acc[m][n] = (f32x4){0.f, 0.f, 0.f, 0.f};

  int cur = 0;
  for (int kt = 0; kt < 4; ++kt) {
    if (kt < 3) {
      int k1 = (kt + 1) * 32;
      int nxt = (cur ^ 1) * 4096;
      gl_lds16(Ag + (size_t)grow0 * 128 + k1 + ak0, &AshD[nxt + c0 * 8]);
      gl_lds16(Ag + (size_t)grow1 * 128 + k1 + ak1, &AshD[nxt + c1 * 8]);
    }
    int cbse = cur * 4096;
    s16x8 af[4], bfr[4];
#pragma unroll
    for (int m = 0; m < 4; ++m) af[m] = *(const s16x8*)&AshD[cbse + aoff[m]];
#pragma unroll
    for (int n = 0; n < 4; ++n) bfr[n] = *(const s16x8*)&Bsh[kt * 4096 + boff[n]];
#pragma unroll
    for (int m = 0; m < 4; ++m)
#pragma unroll
      for (int n = 0; n < 4; ++n)
        acc[m][n] = __builtin_amdgcn_mfma_f32_16x16x32_bf16(af[m], bfr[n], acc[m][n], 0, 0, 0);
    __syncthreads();
    cur ^= 1;
  }
  int rbase = (lane >> 4) * 4;
#pragma unroll
  for (int m = 0; m < 4; ++m) {
    int lrow = wm * 64 + m * 16 + rbase;
#pragma unroll
    for (int n = 0; n < 4; ++n) {
      int col = wn * 64 + n * 16 + lr;
      float bv = (col < 64) ? b4[col] : 0.f;
#pragma unroll
      for (int r = 0; r < 4; ++r)
        Psh[(size_t)(lrow + r) * 128 + col] = __float2bfloat16(acc[m][n][r] + bv);
    }
  }
  __syncthreads();

  int c = tid & 63, grp = tid >> 6;
  for (int g = 0; g < gcnt; ++g) {
    float pr[NNODE];
#pragma unroll
    for (int m = 0; m < NNODE; ++m)
      pr[m] = __bfloat162float(Psh[(size_t)(g * NNODE + m) * 128 + 64 + c]);
#pragma unroll 1
    for (int n = grp; n < NNODE; n += 4) {
      float aa = __bfloat162float(Psh[(size_t)(g * NNODE + n) * 128 + c])
               + dot41_f4(Aash + (g * NNODE + n) * ASTR, pr);
      Ysh[(g * NNODE + n) * 64 + c] = aa > 0.f ? aa : 0.f;
    }
  }
  __syncthreads();

  int j = tid & 31, slot = tid >> 5;
  for (int el = slot; el < 8 * gcnt; el += 8) {
    int e = g0 * 8 + el;
    int node = knn[e];
    int gl = el >> 3;
    const float* fp = &Ysh[(gl * NNODE + node) * 64];
    float a2 = cb[j];
#pragma unroll
    for (int d = 0; d < 64; ++d) a2 += fp[d] * Wsh[d * 32 + j];
    float h = a2 >= 0.f ? a2 : cb[32 + j] * a2;
#pragma unroll
    for (int o = 0; o < 2; ++o) {
      float v = h * cb[64 + j * 2 + o];
      v += __shfl_xor(v, 16, 32); v += __shfl_xor(v, 8, 32);
      v += __shfl_xor(v, 4, 32);  v += __shfl_xor(v, 2, 32);
      v += __shfl_xor(v, 1, 32);
      if (j == 0) out[(size_t)e * 2 + o] = v;
    }
  }
}

// ---------------------------------------------------------------------------
extern "C" void kernel_launch(void* const* d_in, const int* in_sizes, int n_in,
                              void* d_out, int out_size, void* d_ws, size_t ws_size,
                              hipStream_t stream) {
  const float* inputs     = (const float*)d_in[0];
  const float* node_feats = (const float*)d_in[1];
  const float* Aadj       = (const float*)d_in[2];
  const int*   knn        = (const int*)d_in[3];
  const float* conv_w     = (const float*)d_in[4];
  const float* conv_b     = (const float*)d_in[5];
  const float* W1 = (const float*)d_in[6];  const float* b1 = (const float*)d_in[7];
  const float* W2 = (const float*)d_in[8];  const float* b2 = (const float*)d_in[9];
  const float* W3 = (const float*)d_in[10]; const float* b3 = (const float*)d_in[11];
  const float* W4 = (const float*)d_in[12]; const float* b4 = (const float*)d_in[13];
  const float* cls_w1 = (const float*)d_in[14]; const float* cls_b1 = (const float*)d_in[15];
  const float* prelu_a = (const float*)d_in[16];
  const float* cls_w2 = (const float*)d_in[17]; const float* cls_b2 = (const float*)d_in[18];
  float* out = (float*)d_out;

  char* ws = (char*)d_ws;
  char* R1 = ws;                        // x0 (24.2 MB) -> y2 (10.7 MB)
  char* R2 = ws + 24200192;             // y1 (21.5 MB) -> y3 (5.4 MB)
  char* wp = ws + 24200192 + 42991616;
  __hip_bfloat16* B1t = (__hip_bfloat16*)wp;  wp += 1179648;   // 1024 x 576
  __hip_bfloat16* B2t = (__hip_bfloat16*)wp;  wp += 524288;    // 512 x 512
  __hip_bfloat16* B3t = (__hip_bfloat16*)wp;  wp += 131072;    // 256 x 256
  __hip_bfloat16* B4t = (__hip_bfloat16*)wp;  wp += 32768;     // 128 x 128
  float* partial  = (float*)wp;               wp += 256 * 1152 * 4;
  float* statsbuf = (float*)wp;               wp += 1152 * 4;
  float* gbias    = (float*)wp;               wp += 1024 * 4;

  __hip_bfloat16* x0 = (__hip_bfloat16*)R1;

  // K1: fused cast + stats (one pass over node_feats)
  front_kernel<<<256, 576, 0, stream>>>(node_feats, partial, x0);
  // K2: wide BN reduce
  reduce_kernel<<<3, 256, 0, stream>>>(partial, statsbuf);
  // K3: W1 fold-repack + cvec GEMV + W2-4 repack (paired-col permutation)
  wt1_kernel<<<932, 256, 0, stream>>>(W1, b1, statsbuf, B1t, gbias,
                                      W2, W3, W4, B2t, B3t, B4t);

  // L1: 512-thread 256x128 variant (+ trailing conv, 512 blocks of 512 thr)
  gemmagg512_kernel<<<NTMG6 * 8 + 512, 512, 0, stream>>>(
      x0, B1t, gbias, gbias + 512, (__hip_bfloat16*)R2, 512, 576, 8,
      Aadj, inputs, conv_w, conv_b, out);
  // L2: y1 -> y2 (R1), Nout=256, K=512, NTN=4
  gemmagg_kernel<<<NTMG * 4, 256, 0, stream>>>(
      (__hip_bfloat16*)R2, B2t, b2, nullptr, (__hip_bfloat16*)R1, 256, 512, 4,
      Aadj);
  // L3: y2 -> y3 (R2), Nout=128, K=256, NTN=2
  gemmagg_kernel<<<NTMG * 2, 256, 0, stream>>>(
      (__hip_bfloat16*)R1, B3t, b3, nullptr, (__hip_bfloat16*)R2, 128, 256, 2,
      Aadj);
  // L4 fused: gemm + agg + knn classifier
  gemm4cls_kernel<<<171, 256, 0, stream>>>(
      (__hip_bfloat16*)R2, B4t, b4, Aadj, knn, cls_w1, cls_b1, prelu_a,
      cls_w2, cls_b2, out + 6291456);
}

// Round 18
// 240.544 us; speedup vs baseline: 1.1914x; 1.0169x over previous
//
#include <hip/hip_runtime.h>
#include <hip/hip_bf16.h>

// ---------------------------------------------------------------------------
// DRRGHead, 7 dispatches.
//   relu(cat(x_norm, A@x_norm) @ W + b) == relu(x@W' + b' + A@(x@W'_bot))
// BN folded into W1. GEMM+agg fused per layer: M-tile = 3 graphs (123 rows
// pad 128), Bt rows permuted so each 128-row weight tile = 64 L-cols + their
// 64 R-cols; P stays in LDS; y = relu(P_L + A@P_R) written directly.
// R18: conv moved OUT of L1 (2.2-generation grid -> tail serialized ~28us)
//   into the under-subscribed L2 (684 gemm blocks) and L3 (342) grids as
//   zero-LDS tail blocks that co-schedule beyond the GEMM blocks' LDS cap.
//   Everything else = R14 (best measured, 239.2us).
// GEMM core: 128x128, 2-ph dbuf global_load_lds, conflict-free slot-swizzle,
// supergroup swizzle.
// ---------------------------------------------------------------------------

using f32x4 = __attribute__((ext_vector_type(4))) float;
using s16x8 = __attribute__((ext_vector_type(8))) short;   // 8 bf16

#define GN 20992          // G*N rows
#define NFEAT 576
#define NGRAPH 512
#define NNODE 41
#define ASTR 44           // padded A row stride (44 f32 = 176 B, 16B-aligned)
#define NTMG 171          // m-tiles of 3 graphs (123 rows); 171*3 = 513 >= 512

typedef __attribute__((address_space(1))) const unsigned int gas_u32;
typedef __attribute__((address_space(3))) unsigned int las_u32;

__device__ __forceinline__ void gl_lds16(const void* g, void* l) {
  __builtin_amdgcn_global_load_lds((gas_u32*)g, (las_u32*)l, 16, 0, 0);
}

// dot over 41: A row (LDS, 16B-aligned, broadcast) . pr[] (regs), float4 reads
__device__ __forceinline__ float dot41_f4(const float* __restrict__ Am,
                                          const float* __restrict__ pr) {
  float s0 = 0.f, s1 = 0.f, s2 = 0.f, s3 = 0.f;
#pragma unroll
  for (int q = 0; q < 10; ++q) {
    float4 a4 = *(const float4*)(Am + q * 4);
    s0 += a4.x * pr[q * 4];
    s1 += a4.y * pr[q * 4 + 1];
    s2 += a4.z * pr[q * 4 + 2];
    s3 += a4.w * pr[q * 4 + 3];
  }
  return ((s0 + s1) + (s2 + s3)) + Am[40] * pr[40];
}

// ---------------- K1: fused bf16-cast + bn-stats (one pass over nf) ---------
__global__ __launch_bounds__(576) void front_kernel(
    const float* __restrict__ nf, float* __restrict__ partial,
    __hip_bfloat16* __restrict__ x0) {
  int c = threadIdx.x;                  // 0..575
  int u = blockIdx.x;                   // 0..255
  int r0 = u * 82;
  const float* src = nf + (size_t)r0 * NFEAT + c;
  __hip_bfloat16* dst = x0 + (size_t)r0 * NFEAT + c;
  float s = 0.f, s2 = 0.f;
#pragma unroll 4
  for (int r = 0; r < 82; ++r) {
    float v = src[(size_t)r * NFEAT];
    s += v; s2 += v * v;
    dst[(size_t)r * NFEAT] = __float2bfloat16(v);
  }
  partial[(size_t)u * 1152 + c] = s;
  partial[(size_t)u * 1152 + NFEAT + c] = s2;
}

// ---------------- K2: wide BN reduce -> statsbuf = {inv[576], m*inv[576]} ---
__global__ __launch_bounds__(256) void reduce_kernel(
    const float* __restrict__ partial, float* __restrict__ statsbuf) {
  int t = blockIdx.x * 256 + threadIdx.x;
  if (t >= NFEAT) return;
  float s = 0.f, s2 = 0.f;
#pragma unroll 8
  for (int u = 0; u < 256; ++u) {
    s += partial[(size_t)u * 1152 + t];
    s2 += partial[(size_t)u * 1152 + NFEAT + t];
  }
  float m = s * (1.f / GN);
  float v = s2 * (1.f / GN) - m * m;
  float inv = rsqrtf(v + 1e-5f);
  statsbuf[t] = inv;
  statsbuf[NFEAT + t] = m * inv;
}

// ---------------- K3: W1 fold-repack + cvec GEMV + W2-4 repack --------------
// All Bt writes use paired-col permutation jp = (rowh>>6)*128 + h*64 + (rowh&63)
__global__ __launch_bounds__(256) void wt1_kernel(
    const float* __restrict__ W1, const float* __restrict__ b1,
    const float* __restrict__ statsbuf, __hip_bfloat16* __restrict__ B1,
    float* __restrict__ gbias,
    const float* __restrict__ W2, const float* __restrict__ W3,
    const float* __restrict__ W4,
    __hip_bfloat16* __restrict__ B2, __hip_bfloat16* __restrict__ B3,
    __hip_bfloat16* __restrict__ B4) {
  int u = blockIdx.x;
  int tid = threadIdx.x;
  if (u < 576) {                        // fold-repack tile of W1 (2N=1024,K=576)
    __shared__ float T[32 * 33];
    int jt = u / 18, kt = u - jt * 18;
    int j0 = jt * 32, k0 = kt * 32;
    int h = (j0 >= 512) ? 1 : 0;
    const float* Wh = W1 + (size_t)(h * 576) * 512 + (j0 - h * 512);
    int r = tid >> 5, cc = tid & 31;
#pragma unroll
    for (int i = 0; i < 4; ++i)
      T[(r + i * 8) * 33 + cc] = Wh[(size_t)(k0 + r + i * 8) * 512 + cc];
    __syncthreads();
    float invv = statsbuf[k0 + cc];
#pragma unroll
    for (int i = 0; i < 4; ++i) {
      int rowh = (j0 - h * 512) + r + i * 8;
      int jp = (rowh >> 6) * 128 + h * 64 + (rowh & 63);
      B1[(size_t)jp * 576 + k0 + cc] =
          __float2bfloat16(T[cc * 33 + (r + i * 8)] * invv);
    }
  } else if (u < 580) {                 // cvec GEMV (gbias in ORIGINAL order)
    int j = (u - 576) * 256 + tid;      // 0..1023
    int col = (j < 512) ? j : j - 512;
    const float* base = W1 + (size_t)((j < 512) ? 0 : 576) * 512 + col;
    float s = 0.f;
#pragma unroll 4
    for (int f = 0; f < NFEAT; ++f) s += statsbuf[NFEAT + f] * base[(size_t)f * 512];
    gbias[j] = ((j < 512) ? b1[j] : 0.f) - s;
  } else {                              // plain repack W2/W3/W4 (permuted rows)
    __shared__ float T[32 * 33];
    int t = u - 580;
    const float* W; __hip_bfloat16* B; int K, N;
    if (t < 256)      { W = W2; B = B2; K = 512; N = 256; }
    else if (t < 320) { W = W3; B = B3; K = 256; N = 128; t -= 256; }
    else              { W = W4; B = B4; K = 128; N = 64;  t -= 320; }
    int tilesN = N >> 5;
    int perhalf = (K >> 5) * tilesN;
    int h = t / perhalf; t -= h * perhalf;
    int tk = t / tilesN, tn = t - tk * tilesN;
    int r = tid >> 5, cc = tid & 31;
    const float* Wh = W + (size_t)h * K * N;
#pragma unroll
    for (int i = 0; i < 4; ++i)
      T[(r + i * 8) * 33 + cc] = Wh[(size_t)(tk * 32 + r + i * 8) * N + tn * 32 + cc];
    __syncthreads();
#pragma unroll
    for (int i = 0; i < 4; ++i) {
      int row = tn * 32 + r + i * 8;
      int jp = (row >> 6) * 128 + h * 64 + (row & 63);
      B[(size_t)jp * K + tk * 32 + cc] =
          __float2bfloat16(T[cc * 33 + r + i * 8]);
    }
  }
}

// ---------------- fused GEMM + agg: y = relu(P_L + A@P_R), layers 1-3 -------
// M-tile = 3 graphs (123 rows pad 128); N-tile = 64 L-cols + 64 paired R-cols.
// P in LDS (rows 0..122 used); Aash overlays [31488, 53136), filled AFTER the
// K-loop. Blocks >= gemmBlocks run 1x1-conv chunks [convBase, convBase+...).
__global__ __launch_bounds__(256) void gemmagg_kernel(
    const __hip_bfloat16* __restrict__ Xptr, const __hip_bfloat16* __restrict__ Bt,
    const float* __restrict__ biasL, const float* __restrict__ biasR,
    __hip_bfloat16* __restrict__ Yptr, int Nout, int K, int NTN, int convBase,
    const float* __restrict__ Aadj,
    const float* __restrict__ cinputs, const float* __restrict__ conv_w,
    const float* __restrict__ conv_b, float* __restrict__ cout) {
  // LDS map: [0,32768) staging dbuf; Psh rows 0..122 = [0,31488);
  //          Aash (123 x 44 f32 = 21648 B) at [31488, 53136).
  __shared__ __align__(16) char smem[53136];
  short* AshD = (short*)smem;                 // [2][128*32]
  short* BshD = (short*)(smem + 16384);       // [2][128*32]
  __hip_bfloat16* Psh = (__hip_bfloat16*)smem;
  float* Aash = (float*)(smem + 31488);

  int tid = threadIdx.x;
  int bid = blockIdx.x;
  int gemmBlocks = NTMG * NTN;

  if (bid >= gemmBlocks) {              // ---- conv pool (zero-LDS tail)
    int p = (convBase + bid - gemmBlocks) * 256 + tid;
    int img = p >> 16, q = p & 65535;
    const float4* ip = (const float4*)cinputs + (size_t)img * 32 * 65536 + q;
    float4 acc[6];
#pragma unroll
    for (int o = 0; o < 6; ++o) { float b0 = conv_b[o]; acc[o] = make_float4(b0, b0, b0, b0); }
#pragma unroll 4
    for (int c = 0; c < 32; ++c) {
      float4 x = ip[(size_t)c * 65536];
#pragma unroll
      for (int o = 0; o < 6; ++o) {
        float wv = conv_w[o * 32 + c];
        acc[o].x += x.x * wv; acc[o].y += x.y * wv;
        acc[o].z += x.z * wv; acc[o].w += x.w * wv;
      }
    }
    float4* op = (float4*)cout + (size_t)img * 6 * 65536 + q;
#pragma unroll
    for (int o = 0; o < 6; ++o) op[(size_t)o * 65536] = acc[o];
    return;
  }

  int sg = bid / (NTN * 8);
  int rem = bid - sg * (NTN * 8);
  int Wm = NTMG - sg * 8; if (Wm > 8) Wm = 8;
  int mt = sg * 8 + rem % Wm;
  int nt = rem / Wm;
  int row0 = mt * 123;
  int g0 = mt * 3;
  int gcnt = NGRAPH - g0; if (gcnt > 3) gcnt = 3;

  int wave = tid >> 6, lane = tid & 63;
  int wm = wave >> 1, wn = wave & 1;
  int lr = lane & 15, kb = lane >> 4;

  f32x4 acc[4][4];
#pragma unroll
  for (int m = 0; m < 4; ++m)
#pragma unroll
    for (int n = 0; n < 4; ++n) acc[m][n] = (f32x4){0.f, 0.f, 0.f, 0.f};

  const short* Ag = (const short*)Xptr;
  const short* Bg = (const short*)Bt + (size_t)nt * 128 * K;

  // staging: slot c holds global chunk (row = c>>2, k-chunk = (c&3)^((row>>1)&3))
  int c0 = tid, c1 = tid + 256;
  int ar0 = c0 >> 2, ak0 = (((c0 & 3) ^ ((ar0 >> 1) & 3))) * 8;
  int ar1 = c1 >> 2, ak1 = (((c1 & 3) ^ ((ar1 >> 1) & 3))) * 8;
  int grow0 = row0 + ar0; if (grow0 > GN - 1) grow0 = GN - 1;   // pad rows clamp
  int grow1 = row0 + ar1; if (grow1 > GN - 1) grow1 = GN - 1;

  // fragment read offsets (shorts): row*32 + (((row>>1)&3)^kb)*8
  int aoff[4], boff[4];
#pragma unroll
  for (int m = 0; m < 4; ++m) {
    int r = wm * 64 + m * 16 + lr;
    aoff[m] = r * 32 + ((((r >> 1) & 3) ^ kb) * 8);
  }
#pragma unroll
  for (int n = 0; n < 4; ++n) {
    int r = wn * 64 + n * 16 + lr;
    boff[n] = r * 32 + ((((r >> 1) & 3) ^ kb) * 8);
  }

  gl_lds16(Ag + (size_t)grow0 * K + ak0, &AshD[c0 * 8]);
  gl_lds16(Ag + (size_t)grow1 * K + ak1, &AshD[c1 * 8]);
  gl_lds16(Bg + (size_t)ar0 * K + ak0, &BshD[c0 * 8]);
  gl_lds16(Bg + (size_t)ar1 * K + ak1, &BshD[c1 * 8]);
  __syncthreads();

  int nkt = K >> 5;
  int cur = 0;
  for (int kt = 0; kt < nkt; ++kt) {
    if (kt + 1 < nkt) {
      int k1 = (kt + 1) * 32;
      int nxt = (cur ^ 1) * 4096;
      gl_lds16(Ag + (size_t)grow0 * K + k1 + ak0, &AshD[nxt + c0 * 8]);
      gl_lds16(Ag + (size_t)grow1 * K + k1 + ak1, &AshD[nxt + c1 * 8]);
      gl_lds16(Bg + (size_t)ar0 * K + k1 + ak0, &BshD[nxt + c0 * 8]);
      gl_lds16(Bg + (size_t)ar1 * K + k1 + ak1, &BshD[nxt + c1 * 8]);
    }
    int cb = cur * 4096;
    s16x8 af[4], bfr[4];
#pragma unroll
    for (int m = 0; m < 4; ++m) af[m] = *(const s16x8*)&AshD[cb + aoff[m]];
#pragma unroll
    for (int n = 0; n < 4; ++n) bfr[n] = *(const s16x8*)&BshD[cb + boff[n]];
#pragma unroll
    for (int m = 0; m < 4; ++m)
#pragma unroll
      for (int n = 0; n < 4; ++n)
        acc[m][n] = __builtin_amdgcn_mfma_f32_16x16x32_bf16(af[m], bfr[n], acc[m][n], 0, 0, 0);
    __syncthreads();
    cur ^= 1;
  }

  // epilogue 1: P (+bias, both halves) -> Psh overlay (safe: loop ended w/ barrier)
  // rows >= 123 land in the Aash region but are overwritten before use.
  int rbase = (lane >> 4) * 4;
#pragma unroll
  for (int m = 0; m < 4; ++m) {
    int lrow = wm * 64 + m * 16 + rbase;
#pragma unroll
    for (int n = 0; n < 4; ++n) {
      int w = wn * 64 + n * 16 + lr;
      float bv = (w < 64) ? biasL[nt * 64 + w]
                          : (biasR ? biasR[nt * 64 + (w - 64)] : 0.f);
#pragma unroll
      for (int r = 0; r < 4; ++r)
        Psh[(size_t)(lrow + r) * 128 + w] = __float2bfloat16(acc[m][n][r] + bv);
    }
  }
  __syncthreads();

  // A copy: global -> padded LDS rows (stride 44), after P writes done
  {
    int tot = gcnt * (NNODE * NNODE);
    const float* Asrc = Aadj + (size_t)g0 * (NNODE * NNODE);
    for (int i = tid; i < tot; i += 256) {
      int row = i / NNODE, m = i - row * NNODE;
      Aash[row * ASTR + m] = Asrc[i];
    }
  }
  __syncthreads();

  // epilogue 2: y[g][n][c] = relu(P_L[n][c] + dot(A[n,:], P_R[:,c]))
  int c = tid & 63, grp = tid >> 6;
  for (int g = 0; g < gcnt; ++g) {
    float pr[NNODE];
#pragma unroll
    for (int m = 0; m < NNODE; ++m)
      pr[m] = __bfloat162float(Psh[(size_t)(g * NNODE + m) * 128 + 64 + c]);
#pragma unroll 1
    for (int n = grp; n < NNODE; n += 4) {
      float aa = __bfloat162float(Psh[(size_t)(g * NNODE + n) * 128 + c])
               + dot41_f4(Aash + (g * NNODE + n) * ASTR, pr);
      aa = aa > 0.f ? aa : 0.f;
      Yptr[(size_t)(row0 + g * NNODE + n) * Nout + nt * 64 + c] = __float2bfloat16(aa);
    }
  }
}

// ---------------- G4F: gemm4 + agg4 + knn classifier, 3 graphs/block --------
__global__ __launch_bounds__(256) void gemm4cls_kernel(
    const __hip_bfloat16* __restrict__ X, const __hip_bfloat16* __restrict__ B4t,
    const float* __restrict__ b4, const float* __restrict__ Aadj,
    const int* __restrict__ knn, const float* __restrict__ w1,
    const float* __restrict__ cb1, const float* __restrict__ pa,
    const float* __restrict__ w2, const float* __restrict__ cb2,
    float* __restrict__ out) {
  __shared__ __align__(16) char smem[49152 + 21648 + 31488 + 8192 + 520];
  short* AshD = (short*)smem;
  short* Bsh  = (short*)(smem + 16384);
  __hip_bfloat16* Psh = (__hip_bfloat16*)smem;
  float* Aash = (float*)(smem + 49152);                   // 123 x 44 f32 padded
  float* Ysh  = (float*)(smem + 49152 + 21648);
  float* Wsh  = (float*)(smem + 49152 + 21648 + 31488);
  float* cb   = (float*)(smem + 49152 + 21648 + 31488 + 8192);

  int tid = threadIdx.x;
  int blk = blockIdx.x;
  int g0 = blk * 3;
  int gcnt = NGRAPH - g0; if (gcnt > 3) gcnt = 3;
  int row0 = blk * 123;

  {
    int tot = gcnt * (NNODE * NNODE);
    const float* Asrc = Aadj + (size_t)g0 * (NNODE * NNODE);
    for (int i = tid; i < tot; i += 256) {
      int row = i / NNODE, m = i - row * NNODE;
      Aash[row * ASTR + m] = Asrc[i];
    }
  }
  for (int i = tid; i < 2048; i += 256) Wsh[i] = w1[i];
  if (tid < 32) { cb[tid] = cb1[tid]; cb[32 + tid] = pa[tid]; }
  if (tid < 64) cb[64 + tid] = w2[tid];
  if (tid < 2) cb[128 + tid] = cb2[tid];

#pragma unroll
  for (int i = 0; i < 8; ++i) {
    int c = tid + i * 256;              // 2048 chunks of 16B
    int kt = c >> 9, w = c & 511;
    int r = w >> 2, kc = ((w & 3) ^ ((r >> 1) & 3)) * 8;
    gl_lds16((const short*)B4t + (size_t)r * 128 + kt * 32 + kc, &Bsh[c * 8]);
  }
  const short* Ag = (const short*)X;
  int c0 = tid, c1 = tid + 256;
  int ar0 = c0 >> 2, ak0 = (((c0 & 3) ^ ((ar0 >> 1) & 3))) * 8;
  int ar1 = c1 >> 2, ak1 = (((c1 & 3) ^ ((ar1 >> 1) & 3))) * 8;
  int grow0 = row0 + ar0; if (grow0 > GN - 1) grow0 = GN - 1;
  int grow1 = row0 + ar1; if (grow1 > GN - 1) grow1 = GN - 1;
  gl_lds16(Ag + (size_t)grow0 * 128 + ak0, &AshD[c0 * 8]);
  gl_lds16(Ag + (size_t)grow1 * 128 + ak1, &AshD[c1 * 8]);
  __syncthreads();

  int wave = tid >> 6, lane = tid & 63;
  int wm = wave >> 1, wn = wave & 1;
  int lr = lane & 15, kb = lane >> 4;
  int aoff[4], boff[4];
#pragma unroll
  for (int m = 0; m < 4; ++m) {
    int r = wm * 64 + m * 16 + lr;
    aoff[m] = r * 32 + ((((r >> 1) & 3) ^ kb) * 8);
  }
#pragma unroll
  for (int n = 0; n < 4; ++n) {
    int r = wn * 64 + n * 16 + lr;
    boff[n] = r * 32 + ((((r >> 1) & 3) ^ kb) * 8);
  }
  f32x4 acc[4][4];
#pragma unroll
  for (int m = 0; m < 4; ++m)
#pragma unroll
    for (int n = 0; n < 4; ++n) acc[m][n] = (f32x4){0.f, 0.f, 0.f, 0.f};

  int cur = 0;
  for (int kt = 0; kt < 4; ++kt) {
    if (kt < 3) {
      int k1 = (kt + 1) * 32;
      int nxt = (cur ^ 1) * 4096;
      gl_lds16(Ag + (size_t)grow0 * 128 + k1 + ak0, &AshD[nxt + c0 * 8]);
      gl_lds16(Ag + (size_t)grow1 * 128 + k1 + ak1, &AshD[nxt + c1 * 8]);
    }
    int cbse = cur * 4096;
    s16x8 af[4], bfr[4];
#pragma unroll
    for (int m = 0; m < 4; ++m) af[m] = *(const s16x8*)&AshD[cbse + aoff[m]];
#pragma unroll
    for (int n = 0; n < 4; ++n) bfr[n] = *(const s16x8*)&Bsh[kt * 4096 + boff[n]];
#pragma unroll
    for (int m = 0; m < 4; ++m)
#pragma unroll
      for (int n = 0; n < 4; ++n)
        acc[m][n] = __builtin_amdgcn_mfma_f32_16x16x32_bf16(af[m], bfr[n], acc[m][n], 0, 0, 0);
    __syncthreads();
    cur ^= 1;
  }
  int rbase = (lane >> 4) * 4;
#pragma unroll
  for (int m = 0; m < 4; ++m) {
    int lrow = wm * 64 + m * 16 + rbase;
#pragma unroll
    for (int n = 0; n < 4; ++n) {
      int col = wn * 64 + n * 16 + lr;
      float bv = (col < 64) ? b4[col] : 0.f;
#pragma unroll
      for (int r = 0; r < 4; ++r)
        Psh[(size_t)(lrow + r) * 128 + col] = __float2bfloat16(acc[m][n][r] + bv);
    }
  }
  __syncthreads();

  int c = tid & 63, grp = tid >> 6;
  for (int g = 0; g < gcnt; ++g) {
    float pr[NNODE];
#pragma unroll
    for (int m = 0; m < NNODE; ++m)
      pr[m] = __bfloat162float(Psh[(size_t)(g * NNODE + m) * 128 + 64 + c]);
#pragma unroll 1
    for (int n = grp; n < NNODE; n += 4) {
      float aa = __bfloat162float(Psh[(size_t)(g * NNODE + n) * 128 + c])
               + dot41_f4(Aash + (g * NNODE + n) * ASTR, pr);
      Ysh[(g * NNODE + n) * 64 + c] = aa > 0.f ? aa : 0.f;
    }
  }
  __syncthreads();

  int j = tid & 31, slot = tid >> 5;
  for (int el = slot; el < 8 * gcnt; el += 8) {
    int e = g0 * 8 + el;
    int node = knn[e];
    int gl = el >> 3;
    const float* fp = &Ysh[(gl * NNODE + node) * 64];
    float a2 = cb[j];
#pragma unroll
    for (int d = 0; d < 64; ++d) a2 += fp[d] * Wsh[d * 32 + j];
    float h = a2 >= 0.f ? a2 : cb[32 + j] * a2;
#pragma unroll
    for (int o = 0; o < 2; ++o) {
      float v = h * cb[64 + j * 2 + o];
      v += __shfl_xor(v, 16, 32); v += __shfl_xor(v, 8, 32);
      v += __shfl_xor(v, 4, 32);  v += __shfl_xor(v, 2, 32);
      v += __shfl_xor(v, 1, 32);
      if (j == 0) out[(size_t)e * 2 + o] = v;
    }
  }
}

// ---------------------------------------------------------------------------
extern "C" void kernel_launch(void* const* d_in, const int* in_sizes, int n_in,
                              void* d_out, int out_size, void* d_ws, size_t ws_size,
                              hipStream_t stream) {
  const float* inputs     = (const float*)d_in[0];
  const float* node_feats = (const float*)d_in[1];
  const float* Aadj       = (const float*)d_in[2];
  const int*   knn        = (const int*)d_in[3];
  const float* conv_w     = (const float*)d_in[4];
  const float* conv_b     = (const float*)d_in[5];
  const float* W1 = (const float*)d_in[6];  const float* b1 = (const float*)d_in[7];
  const float* W2 = (const float*)d_in[8];  const float* b2 = (const float*)d_in[9];
  const float* W3 = (const float*)d_in[10]; const float* b3 = (const float*)d_in[11];
  const float* W4 = (const float*)d_in[12]; const float* b4 = (const float*)d_in[13];
  const float* cls_w1 = (const float*)d_in[14]; const float* cls_b1 = (const float*)d_in[15];
  const float* prelu_a = (const float*)d_in[16];
  const float* cls_w2 = (const float*)d_in[17]; const float* cls_b2 = (const float*)d_in[18];
  float* out = (float*)d_out;

  char* ws = (char*)d_ws;
  char* R1 = ws;                        // x0 (24.2 MB) -> y2 (10.7 MB)
  char* R2 = ws + 24200192;             // y1 (21.5 MB) -> y3 (5.4 MB)
  char* wp = ws + 24200192 + 42991616;
  __hip_bfloat16* B1t = (__hip_bfloat16*)wp;  wp += 1179648;   // 1024 x 576
  __hip_bfloat16* B2t = (__hip_bfloat16*)wp;  wp += 524288;    // 512 x 512
  __hip_bfloat16* B3t = (__hip_bfloat16*)wp;  wp += 131072;    // 256 x 256
  __hip_bfloat16* B4t = (__hip_bfloat16*)wp;  wp += 32768;     // 128 x 128
  float* partial  = (float*)wp;               wp += 256 * 1152 * 4;
  float* statsbuf = (float*)wp;               wp += 1152 * 4;
  float* gbias    = (float*)wp;               wp += 1024 * 4;

  __hip_bfloat16* x0 = (__hip_bfloat16*)R1;

  // K1: fused cast + stats (one pass over node_feats)
  front_kernel<<<256, 576, 0, stream>>>(node_feats, partial, x0);
  // K2: wide BN reduce
  reduce_kernel<<<3, 256, 0, stream>>>(partial, statsbuf);
  // K3: W1 fold-repack + cvec GEMV + W2-4 repack (paired-col permutation)
  wt1_kernel<<<932, 256, 0, stream>>>(W1, b1, statsbuf, B1t, gbias,
                                      W2, W3, W4, B2t, B3t, B4t);

  // L1 fused gemm+agg (no conv): x0 -> y1 (R2), Nout=512, K=576, NTN=8
  gemmagg_kernel<<<NTMG * 8, 256, 0, stream>>>(
      x0, B1t, gbias, gbias + 512, (__hip_bfloat16*)R2, 512, 576, 8, 0,
      Aadj, nullptr, nullptr, nullptr, nullptr);
  // L2 (+ conv chunks 0..511): y1 -> y2 (R1), Nout=256, K=512, NTN=4
  gemmagg_kernel<<<NTMG * 4 + 512, 256, 0, stream>>>(
      (__hip_bfloat16*)R2, B2t, b2, nullptr, (__hip_bfloat16*)R1, 256, 512, 4,
      0, Aadj, inputs, conv_w, conv_b, out);
  // L3 (+ conv chunks 512..1023): y2 -> y3 (R2), Nout=128, K=256, NTN=2
  gemmagg_kernel<<<NTMG * 2 + 512, 256, 0, stream>>>(
      (__hip_bfloat16*)R1, B3t, b3, nullptr, (__hip_bfloat16*)R2, 128, 256, 2,
      512, Aadj, inputs, conv_w, conv_b, out);
  // L4 fused: gemm + agg + knn classifier
  gemm4cls_kernel<<<171, 256, 0, stream>>>(
      (__hip_bfloat16*)R2, B4t, b4, Aadj, knn, cls_w1, cls_b1, prelu_a,
      cls_w2, cls_b2, out + 6291456);
}

// Round 19
// 236.668 us; speedup vs baseline: 1.2109x; 1.0164x over previous
//
#include <hip/hip_runtime.h>
#include <hip/hip_bf16.h>

// ---------------------------------------------------------------------------
// DRRGHead, 7 dispatches.
//   relu(cat(x_norm, A@x_norm) @ W + b) == relu(x@W' + b' + A@(x@W'_bot))
// BN folded into W1. GEMM+agg fused per layer: M-tile = 3 graphs (123 rows
// pad 128), Bt rows permuted so each 128-row weight tile = 64 L-cols + their
// 64 R-cols; P stays in LDS; y = relu(P_L + A@P_R) written directly.
// R19: K-loop rebuilt as a 3-STAGE COUNTED-VMCNT PIPELINE (T3/T4): raw
//   s_barrier + s_waitcnt vmcnt(8/4/0) + sched_barrier fences replace
//   __syncthreads()'s forced vmcnt(0) drain; prefetch gets 2 K-steps of
//   latency cover. Staging 3x16KB; Psh/Aash overlays unchanged (53,136 B,
//   3 blocks/CU). Conv chunks remain in L2/L3 tails (R18).
// ---------------------------------------------------------------------------

using f32x4 = __attribute__((ext_vector_type(4))) float;
using s16x8 = __attribute__((ext_vector_type(8))) short;   // 8 bf16

#define GN 20992          // G*N rows
#define NFEAT 576
#define NGRAPH 512
#define NNODE 41
#define ASTR 44           // padded A row stride (44 f32 = 176 B, 16B-aligned)
#define NTMG 171          // m-tiles of 3 graphs (123 rows); 171*3 = 513 >= 512

typedef __attribute__((address_space(1))) const unsigned int gas_u32;
typedef __attribute__((address_space(3))) unsigned int las_u32;

__device__ __forceinline__ void gl_lds16(const void* g, void* l) {
  __builtin_amdgcn_global_load_lds((gas_u32*)g, (las_u32*)l, 16, 0, 0);
}

// dot over 41: A row (LDS, 16B-aligned, broadcast) . pr[] (regs), float4 reads
__device__ __forceinline__ float dot41_f4(const float* __restrict__ Am,
                                          const float* __restrict__ pr) {
  float s0 = 0.f, s1 = 0.f, s2 = 0.f, s3 = 0.f;
#pragma unroll
  for (int q = 0; q < 10; ++q) {
    float4 a4 = *(const float4*)(Am + q * 4);
    s0 += a4.x * pr[q * 4];
    s1 += a4.y * pr[q * 4 + 1];
    s2 += a4.z * pr[q * 4 + 2];
    s3 += a4.w * pr[q * 4 + 3];
  }
  return ((s0 + s1) + (s2 + s3)) + Am[40] * pr[40];
}

// ---------------- K1: fused bf16-cast + bn-stats (one pass over nf) ---------
__global__ __launch_bounds__(576) void front_kernel(
    const float* __restrict__ nf, float* __restrict__ partial,
    __hip_bfloat16* __restrict__ x0) {
  int c = threadIdx.x;                  // 0..575
  int u = blockIdx.x;                   // 0..255
  int r0 = u * 82;
  const float* src = nf + (size_t)r0 * NFEAT + c;
  __hip_bfloat16* dst = x0 + (size_t)r0 * NFEAT + c;
  float s = 0.f, s2 = 0.f;
#pragma unroll 4
  for (int r = 0; r < 82; ++r) {
    float v = src[(size_t)r * NFEAT];
    s += v; s2 += v * v;
    dst[(size_t)r * NFEAT] = __float2bfloat16(v);
  }
  partial[(size_t)u * 1152 + c] = s;
  partial[(size_t)u * 1152 + NFEAT + c] = s2;
}

// ---------------- K2: wide BN reduce -> statsbuf = {inv[576], m*inv[576]} ---
__global__ __launch_bounds__(256) void reduce_kernel(
    const float* __restrict__ partial, float* __restrict__ statsbuf) {
  int t = blockIdx.x * 256 + threadIdx.x;
  if (t >= NFEAT) return;
  float s = 0.f, s2 = 0.f;
#pragma unroll 8
  for (int u = 0; u < 256; ++u) {
    s += partial[(size_t)u * 1152 + t];
    s2 += partial[(size_t)u * 1152 + NFEAT + t];
  }
  float m = s * (1.f / GN);
  float v = s2 * (1.f / GN) - m * m;
  float inv = rsqrtf(v + 1e-5f);
  statsbuf[t] = inv;
  statsbuf[NFEAT + t] = m * inv;
}

// ---------------- K3: W1 fold-repack + cvec GEMV + W2-4 repack --------------
// All Bt writes use paired-col permutation jp = (rowh>>6)*128 + h*64 + (rowh&63)
__global__ __launch_bounds__(256) void wt1_kernel(
    const float* __restrict__ W1, const float* __restrict__ b1,
    const float* __restrict__ statsbuf, __hip_bfloat16* __restrict__ B1,
    float* __restrict__ gbias,
    const float* __restrict__ W2, const float* __restrict__ W3,
    const float* __restrict__ W4,
    __hip_bfloat16* __restrict__ B2, __hip_bfloat16* __restrict__ B3,
    __hip_bfloat16* __restrict__ B4) {
  int u = blockIdx.x;
  int tid = threadIdx.x;
  if (u < 576) {                        // fold-repack tile of W1 (2N=1024,K=576)
    __shared__ float T[32 * 33];
    int jt = u / 18, kt = u - jt * 18;
    int j0 = jt * 32, k0 = kt * 32;
    int h = (j0 >= 512) ? 1 : 0;
    const float* Wh = W1 + (size_t)(h * 576) * 512 + (j0 - h * 512);
    int r = tid >> 5, cc = tid & 31;
#pragma unroll
    for (int i = 0; i < 4; ++i)
      T[(r + i * 8) * 33 + cc] = Wh[(size_t)(k0 + r + i * 8) * 512 + cc];
    __syncthreads();
    float invv = statsbuf[k0 + cc];
#pragma unroll
    for (int i = 0; i < 4; ++i) {
      int rowh = (j0 - h * 512) + r + i * 8;
      int jp = (rowh >> 6) * 128 + h * 64 + (rowh & 63);
      B1[(size_t)jp * 576 + k0 + cc] =
          __float2bfloat16(T[cc * 33 + (r + i * 8)] * invv);
    }
  } else if (u < 580) {                 // cvec GEMV (gbias in ORIGINAL order)
    int j = (u - 576) * 256 + tid;      // 0..1023
    int col = (j < 512) ? j : j - 512;
    const float* base = W1 + (size_t)((j < 512) ? 0 : 576) * 512 + col;
    float s = 0.f;
#pragma unroll 4
    for (int f = 0; f < NFEAT; ++f) s += statsbuf[NFEAT + f] * base[(size_t)f * 512];
    gbias[j] = ((j < 512) ? b1[j] : 0.f) - s;
  } else {                              // plain repack W2/W3/W4 (permuted rows)
    __shared__ float T[32 * 33];
    int t = u - 580;
    const float* W; __hip_bfloat16* B; int K, N;
    if (t < 256)      { W = W2; B = B2; K = 512; N = 256; }
    else if (t < 320) { W = W3; B = B3; K = 256; N = 128; t -= 256; }
    else              { W = W4; B = B4; K = 128; N = 64;  t -= 320; }
    int tilesN = N >> 5;
    int perhalf = (K >> 5) * tilesN;
    int h = t / perhalf; t -= h * perhalf;
    int tk = t / tilesN, tn = t - tk * tilesN;
    int r = tid >> 5, cc = tid & 31;
    const float* Wh = W + (size_t)h * K * N;
#pragma unroll
    for (int i = 0; i < 4; ++i)
      T[(r + i * 8) * 33 + cc] = Wh[(size_t)(tk * 32 + r + i * 8) * N + tn * 32 + cc];
    __syncthreads();
#pragma unroll
    for (int i = 0; i < 4; ++i) {
      int row = tn * 32 + r + i * 8;
      int jp = (row >> 6) * 128 + h * 64 + (row & 63);
      B[(size_t)jp * K + tk * 32 + cc] =
          __float2bfloat16(T[cc * 33 + r + i * 8]);
    }
  }
}

// ---------------- fused GEMM + agg: y = relu(P_L + A@P_R), layers 1-3 -------
// M-tile = 3 graphs (123 rows pad 128); N-tile = 64 L-cols + 64 paired R-cols.
// K-loop: 3-stage counted-vmcnt pipeline (raw s_barrier, no vmcnt(0) drain).
// P in LDS rows 0..122; Aash overlays [31488, 53136), filled AFTER the
// K-loop. Blocks >= gemmBlocks run 1x1-conv chunks [convBase, ...).
__global__ __launch_bounds__(256) void gemmagg_kernel(
    const __hip_bfloat16* __restrict__ Xptr, const __hip_bfloat16* __restrict__ Bt,
    const float* __restrict__ biasL, const float* __restrict__ biasR,
    __hip_bfloat16* __restrict__ Yptr, int Nout, int K, int NTN, int convBase,
    const float* __restrict__ Aadj,
    const float* __restrict__ cinputs, const float* __restrict__ conv_w,
    const float* __restrict__ conv_b, float* __restrict__ cout) {
  // LDS map: A stages [0,24576) (3 x 8192B); B stages [24576,49152);
  //          Psh rows 0..122 overlay [0,31488); Aash at [31488, 53136).
  __shared__ __align__(16) char smem[53136];
  short* AshD = (short*)smem;                 // [3][128*32]
  short* BshD = (short*)(smem + 24576);       // [3][128*32]
  __hip_bfloat16* Psh = (__hip_bfloat16*)smem;
  float* Aash = (float*)(smem + 31488);

  int tid = threadIdx.x;
  int bid = blockIdx.x;
  int gemmBlocks = NTMG * NTN;

  if (bid >= gemmBlocks) {              // ---- conv pool (zero-LDS tail)
    int p = (convBase + bid - gemmBlocks) * 256 + tid;
    int img = p >> 16, q = p & 65535;
    const float4* ip = (const float4*)cinputs + (size_t)img * 32 * 65536 + q;
    float4 acc[6];
#pragma unroll
    for (int o = 0; o < 6; ++o) { float b0 = conv_b[o]; acc[o] = make_float4(b0, b0, b0, b0); }
#pragma unroll 4
    for (int c = 0; c < 32; ++c) {
      float4 x = ip[(size_t)c * 65536];
#pragma unroll
      for (int o = 0; o < 6; ++o) {
        float wv = conv_w[o * 32 + c];
        acc[o].x += x.x * wv; acc[o].y += x.y * wv;
        acc[o].z += x.z * wv; acc[o].w += x.w * wv;
      }
    }
    float4* op = (float4*)cout + (size_t)img * 6 * 65536 + q;
#pragma unroll
    for (int o = 0; o < 6; ++o) op[(size_t)o * 65536] = acc[o];
    return;
  }

  int sg = bid / (NTN * 8);
  int rem = bid - sg * (NTN * 8);
  int Wm = NTMG - sg * 8; if (Wm > 8) Wm = 8;
  int mt = sg * 8 + rem % Wm;
  int nt = rem / Wm;
  int row0 = mt * 123;
  int g0 = mt * 3;
  int gcnt = NGRAPH - g0; if (gcnt > 3) gcnt = 3;

  int wave = tid >> 6, lane = tid & 63;
  int wm = wave >> 1, wn = wave & 1;
  int lr = lane & 15, kb = lane >> 4;

  f32x4 acc[4][4];
#pragma unroll
  for (int m = 0; m < 4; ++m)
#pragma unroll
    for (int n = 0; n < 4; ++n) acc[m][n] = (f32x4){0.f, 0.f, 0.f, 0.f};

  const short* Ag = (const short*)Xptr;
  const short* Bg = (const short*)Bt + (size_t)nt * 128 * K;

  // staging: slot c holds global chunk (row = c>>2, k-chunk = (c&3)^((row>>1)&3))
  int c0 = tid, c1 = tid + 256;
  int ar0 = c0 >> 2, ak0 = (((c0 & 3) ^ ((ar0 >> 1) & 3))) * 8;
  int ar1 = c1 >> 2, ak1 = (((c1 & 3) ^ ((ar1 >> 1) & 3))) * 8;
  int grow0 = row0 + ar0; if (grow0 > GN - 1) grow0 = GN - 1;   // pad rows clamp
  int grow1 = row0 + ar1; if (grow1 > GN - 1) grow1 = GN - 1;

  // fragment read offsets (shorts): row*32 + (((row>>1)&3)^kb)*8
  int aoff[4], boff[4];
#pragma unroll
  for (int m = 0; m < 4; ++m) {
    int r = wm * 64 + m * 16 + lr;
    aoff[m] = r * 32 + ((((r >> 1) & 3) ^ kb) * 8);
  }
#pragma unroll
  for (int n = 0; n < 4; ++n) {
    int r = wn * 64 + n * 16 + lr;
    boff[n] = r * 32 + ((((r >> 1) & 3) ^ kb) * 8);
  }

  int nkt = K >> 5;
  // prologue: issue stages 0..2 (4 loads/thread each, 12 outstanding)
#pragma unroll
  for (int s = 0; s < 3; ++s) {
    int k0 = s * 32;
    gl_lds16(Ag + (size_t)grow0 * K + k0 + ak0, &AshD[s * 4096 + c0 * 8]);
    gl_lds16(Ag + (size_t)grow1 * K + k0 + ak1, &AshD[s * 4096 + c1 * 8]);
    gl_lds16(Bg + (size_t)ar0 * K + k0 + ak0, &BshD[s * 4096 + c0 * 8]);
    gl_lds16(Bg + (size_t)ar1 * K + k0 + ak1, &BshD[s * 4096 + c1 * 8]);
  }

  for (int kt = 0; kt < nkt; ++kt) {
    int remS = nkt - kt;                // stages not yet computed
    if (remS >= 3)      asm volatile("s_waitcnt vmcnt(8)" ::: "memory");
    else if (remS == 2) asm volatile("s_waitcnt vmcnt(4)" ::: "memory");
    else                asm volatile("s_waitcnt vmcnt(0)" ::: "memory");
    __builtin_amdgcn_sched_barrier(0);
    __builtin_amdgcn_s_barrier();       // stage kt resident for all waves
    __builtin_amdgcn_sched_barrier(0);

    int cb = (kt % 3) * 4096;
    s16x8 af[4], bfr[4];
#pragma unroll
    for (int m = 0; m < 4; ++m) af[m] = *(const s16x8*)&AshD[cb + aoff[m]];
#pragma unroll
    for (int n = 0; n < 4; ++n) bfr[n] = *(const s16x8*)&BshD[cb + boff[n]];
#pragma unroll
    for (int m = 0; m < 4; ++m)
#pragma unroll
      for (int n = 0; n < 4; ++n)
        acc[m][n] = __builtin_amdgcn_mfma_f32_16x16x32_bf16(af[m], bfr[n], acc[m][n], 0, 0, 0);

    __builtin_amdgcn_sched_barrier(0);
    __builtin_amdgcn_s_barrier();       // all waves done reading buf[kt%3]
    __builtin_amdgcn_sched_barrier(0);
    if (kt + 3 < nkt) {                 // refill the just-freed buffer
      int k1 = (kt + 3) * 32;
      gl_lds16(Ag + (size_t)grow0 * K + k1 + ak0, &AshD[cb + c0 * 8]);
      gl_lds16(Ag + (size_t)grow1 * K + k1 + ak1, &AshD[cb + c1 * 8]);
      gl_lds16(Bg + (size_t)ar0 * K + k1 + ak0, &BshD[cb + c0 * 8]);
      gl_lds16(Bg + (size_t)ar1 * K + k1 + ak1, &BshD[cb + c1 * 8]);
    }
  }
  // loop ended with a full barrier; vmcnt drained at last iteration's wait.

  // epilogue 1: P (+bias, both halves) -> Psh overlay
  // rows >= 123 land in the Aash region but are overwritten before use.
  int rbase = (lane >> 4) * 4;
#pragma unroll
  for (int m = 0; m < 4; ++m) {
    int lrow = wm * 64 + m * 16 + rbase;
#pragma unroll
    for (int n = 0; n < 4; ++n) {
      int w = wn * 64 + n * 16 + lr;
      float bv = (w < 64) ? biasL[nt * 64 + w]
                          : (biasR ? biasR[nt * 64 + (w - 64)] : 0.f);
#pragma unroll
      for (int r = 0; r < 4; ++r)
        Psh[(size_t)(lrow + r) * 128 + w] = __float2bfloat16(acc[m][n][r] + bv);
    }
  }
  __syncthreads();

  // A copy: global -> padded LDS rows (stride 44), after P writes done
  {
    int tot = gcnt * (NNODE * NNODE);
    const float* Asrc = Aadj + (size_t)g0 * (NNODE * NNODE);
    for (int i = tid; i < tot; i += 256) {
      int row = i / NNODE, m = i - row * NNODE;
      Aash[row * ASTR + m] = Asrc[i];
    }
  }
  __syncthreads();

  // epilogue 2: y[g][n][c] = relu(P_L[n][c] + dot(A[n,:], P_R[:,c]))
  int c = tid & 63, grp = tid >> 6;
  for (int g = 0; g < gcnt; ++g) {
    float pr[NNODE];
#pragma unroll
    for (int m = 0; m < NNODE; ++m)
      pr[m] = __bfloat162float(Psh[(size_t)(g * NNODE + m) * 128 + 64 + c]);
#pragma unroll 1
    for (int n = grp; n < NNODE; n += 4) {
      float aa = __bfloat162float(Psh[(size_t)(g * NNODE + n) * 128 + c])
               + dot41_f4(Aash + (g * NNODE + n) * ASTR, pr);
      aa = aa > 0.f ? aa : 0.f;
      Yptr[(size_t)(row0 + g * NNODE + n) * Nout + nt * 64 + c] = __float2bfloat16(aa);
    }
  }
}

// ---------------- G4F: gemm4 + agg4 + knn classifier, 3 graphs/block --------
__global__ __launch_bounds__(256) void gemm4cls_kernel(
    const __hip_bfloat16* __restrict__ X, const __hip_bfloat16* __restrict__ B4t,
    const float* __restrict__ b4, const float* __restrict__ Aadj,
    const int* __restrict__ knn, const float* __restrict__ w1,
    const float* __restrict__ cb1, const float* __restrict__ pa,
    const float* __restrict__ w2, const float* __restrict__ cb2,
    float* __restrict__ out) {
  __shared__ __align__(16) char smem[49152 + 21648 + 31488 + 8192 + 520];
  short* AshD = (short*)smem;
  short* Bsh  = (short*)(smem + 16384);
  __hip_bfloat16* Psh = (__hip_bfloat16*)smem;
  float* Aash = (float*)(smem + 49152);                   // 123 x 44 f32 padded
  float* Ysh  = (float*)(smem + 49152 + 21648);
  float* Wsh  = (float*)(smem + 49152 + 21648 + 31488);
  float* cb   = (float*)(smem + 49152 + 21648 + 31488 + 8192);

  int tid = threadIdx.x;
  int blk = blockIdx.x;
  int g0 = blk * 3;
  int gcnt = NGRAPH - g0; if (gcnt > 3) gcnt = 3;
  int row0 = blk * 123;

  {
    int tot = gcnt * (NNODE * NNODE);
    const float* Asrc = Aadj + (size_t)g0 * (NNODE * NNODE);
    for (int i = tid; i < tot; i += 256) {
      int row = i / NNODE, m = i - row * NNODE;
      Aash[row * ASTR + m] = Asrc[i];
    }
  }
  for (int i = tid; i < 2048; i += 256) Wsh[i] = w1[i];
  if (tid < 32) { cb[tid] = cb1[tid]; cb[32 + tid] = pa[tid]; }
  if (tid < 64) cb[64 + tid] = w2[tid];
  if (tid < 2) cb[128 + tid] = cb2[tid];

#pragma unroll
  for (int i = 0; i < 8; ++i) {
    int c = tid + i * 256;              // 2048 chunks of 16B
    int kt = c >> 9, w = c & 511;
    int r = w >> 2, kc = ((w & 3) ^ ((r >> 1) & 3)) * 8;
    gl_lds16((const short*)B4t + (size_t)r * 128 + kt * 32 + kc, &Bsh[c * 8]);
  }
  const short* Ag = (const short*)X;
  int c0 = tid, c1 = tid + 256;
  int ar0 = c0 >> 2, ak0 = (((c0 & 3) ^ ((ar0 >> 1) & 3))) * 8;
  int ar1 = c1 >> 2, ak1 = (((c1 & 3) ^ ((ar1 >> 1) & 3))) * 8;
  int grow0 = row0 + ar0; if (grow0 > GN - 1) grow0 = GN - 1;
  int grow1 = row0 + ar1; if (grow1 > GN - 1) grow1 = GN - 1;
  gl_lds16(Ag + (size_t)grow0 * 128 + ak0, &AshD[c0 * 8]);
  gl_lds16(Ag + (size_t)grow1 * 128 + ak1, &AshD[c1 * 8]);
  __syncthreads();

  int wave = tid >> 6, lane = tid & 63;
  int wm = wave >> 1, wn = wave & 1;
  int lr = lane & 15, kb = lane >> 4;
  int aoff[4], boff[4];
#pragma unroll
  for (int m = 0; m < 4; ++m) {
    int r = wm * 64 + m * 16 + lr;
    aoff[m] = r * 32 + ((((r >> 1) & 3) ^ kb) * 8);
  }
#pragma unroll
  for (int n = 0; n < 4; ++n) {
    int r = wn * 64 + n * 16 + lr;
    boff[n] = r * 32 + ((((r >> 1) & 3) ^ kb) * 8);
  }
  f32x4 acc[4][4];
#pragma unroll
  for (int m = 0; m < 4; ++m)
#pragma unroll
    for (int n = 0; n < 4; ++n) acc[m][n] = (f32x4){0.f, 0.f, 0.f, 0.f};

  int cur = 0;
  for (int kt = 0; kt < 4; ++kt) {
    if (kt < 3) {
      int k1 = (kt + 1) * 32;
      int nxt = (cur ^ 1) * 4096;
      gl_lds16(Ag + (size_t)grow0 * 128 + k1 + ak0, &AshD[nxt + c0 * 8]);
      gl_lds16(Ag + (size_t)grow1 * 128 + k1 + ak1, &AshD[nxt + c1 * 8]);
    }
    int cbse = cur * 4096;
    s16x8 af[4], bfr[4];
#pragma unroll
    for (int m = 0; m < 4; ++m) af[m] = *(const s16x8*)&AshD[cbse + aoff[m]];
#pragma unroll
    for (int n = 0; n < 4; ++n) bfr[n] = *(const s16x8*)&Bsh[kt * 4096 + boff[n]];
#pragma unroll
    for (int m = 0; m < 4; ++m)
#pragma unroll
      for (int n = 0; n < 4; ++n)
        acc[m][n] = __builtin_amdgcn_mfma_f32_16x16x32_bf16(af[m], bfr[n], acc[m][n], 0, 0, 0);
    __syncthreads();
    cur ^= 1;
  }
  int rbase = (lane >> 4) * 4;
#pragma unroll
  for (int m = 0; m < 4; ++m) {
    int lrow = wm * 64 + m * 16 + rbase;
#pragma unroll
    for (int n = 0; n < 4; ++n) {
      int col = wn * 64 + n * 16 + lr;
      float bv = (col < 64) ? b4[col] : 0.f;
#pragma unroll
      for (int r = 0; r < 4; ++r)
        Psh[(size_t)(lrow + r) * 128 + col] = __float2bfloat16(acc[m][n][r] + bv);
    }
  }
  __syncthreads();

  int c = tid & 63, grp = tid >> 6;
  for (int g = 0; g < gcnt; ++g) {
    float pr[NNODE];
#pragma unroll
    for (int m = 0; m < NNODE; ++m)
      pr[m] = __bfloat162float(Psh[(size_t)(g * NNODE + m) * 128 + 64 + c]);
#pragma unroll 1
    for (int n = grp; n < NNODE; n += 4) {
      float aa = __bfloat162float(Psh[(size_t)(g * NNODE + n) * 128 + c])
               + dot41_f4(Aash + (g * NNODE + n) * ASTR, pr);
      Ysh[(g * NNODE + n) * 64 + c] = aa > 0.f ? aa : 0.f;
    }
  }
  __syncthreads();

  int j = tid & 31, slot = tid >> 5;
  for (int el = slot; el < 8 * gcnt; el += 8) {
    int e = g0 * 8 + el;
    int node = knn[e];
    int gl = el >> 3;
    const float* fp = &Ysh[(gl * NNODE + node) * 64];
    float a2 = cb[j];
#pragma unroll
    for (int d = 0; d < 64; ++d) a2 += fp[d] * Wsh[d * 32 + j];
    float h = a2 >= 0.f ? a2 : cb[32 + j] * a2;
#pragma unroll
    for (int o = 0; o < 2; ++o) {
      float v = h * cb[64 + j * 2 + o];
      v += __shfl_xor(v, 16, 32); v += __shfl_xor(v, 8, 32);
      v += __shfl_xor(v, 4, 32);  v += __shfl_xor(v, 2, 32);
      v += __shfl_xor(v, 1, 32);
      if (j == 0) out[(size_t)e * 2 + o] = v;
    }
  }
}

// ---------------------------------------------------------------------------
extern "C" void kernel_launch(void* const* d_in, const int* in_sizes, int n_in,
                              void* d_out, int out_size, void* d_ws, size_t ws_size,
                              hipStream_t stream) {
  const float* inputs     = (const float*)d_in[0];
  const float* node_feats = (const float*)d_in[1];
  const float* Aadj       = (const float*)d_in[2];
  const int*   knn        = (const int*)d_in[3];
  const float* conv_w     = (const float*)d_in[4];
  const float* conv_b     = (const float*)d_in[5];
  const float* W1 = (const float*)d_in[6];  const float* b1 = (const float*)d_in[7];
  const float* W2 = (const float*)d_in[8];  const float* b2 = (const float*)d_in[9];
  const float* W3 = (const float*)d_in[10]; const float* b3 = (const float*)d_in[11];
  const float* W4 = (const float*)d_in[12]; const float* b4 = (const float*)d_in[13];
  const float* cls_w1 = (const float*)d_in[14]; const float* cls_b1 = (const float*)d_in[15];
  const float* prelu_a = (const float*)d_in[16];
  const float* cls_w2 = (const float*)d_in[17]; const float* cls_b2 = (const float*)d_in[18];
  float* out = (float*)d_out;

  char* ws = (char*)d_ws;
  char* R1 = ws;                        // x0 (24.2 MB) -> y2 (10.7 MB)
  char* R2 = ws + 24200192;             // y1 (21.5 MB) -> y3 (5.4 MB)
  char* wp = ws + 24200192 + 42991616;
  __hip_bfloat16* B1t = (__hip_bfloat16*)wp;  wp += 1179648;   // 1024 x 576
  __hip_bfloat16* B2t = (__hip_bfloat16*)wp;  wp += 524288;    // 512 x 512
  __hip_bfloat16* B3t = (__hip_bfloat16*)wp;  wp += 131072;    // 256 x 256
  __hip_bfloat16* B4t = (__hip_bfloat16*)wp;  wp += 32768;     // 128 x 128
  float* partial  = (float*)wp;               wp += 256 * 1152 * 4;
  float* statsbuf = (float*)wp;               wp += 1152 * 4;
  float* gbias    = (float*)wp;               wp += 1024 * 4;

  __hip_bfloat16* x0 = (__hip_bfloat16*)R1;

  // K1: fused cast + stats (one pass over node_feats)
  front_kernel<<<256, 576, 0, stream>>>(node_feats, partial, x0);
  // K2: wide BN reduce
  reduce_kernel<<<3, 256, 0, stream>>>(partial, statsbuf);
  // K3: W1 fold-repack + cvec GEMV + W2-4 repack (paired-col permutation)
  wt1_kernel<<<932, 256, 0, stream>>>(W1, b1, statsbuf, B1t, gbias,
                                      W2, W3, W4, B2t, B3t, B4t);

  // L1 fused gemm+agg (no conv): x0 -> y1 (R2), Nout=512, K=576, NTN=8
  gemmagg_kernel<<<NTMG * 8, 256, 0, stream>>>(
      x0, B1t, gbias, gbias + 512, (__hip_bfloat16*)R2, 512, 576, 8, 0,
      Aadj, nullptr, nullptr, nullptr, nullptr);
  // L2 (+ conv chunks 0..511): y1 -> y2 (R1), Nout=256, K=512, NTN=4
  gemmagg_kernel<<<NTMG * 4 + 512, 256, 0, stream>>>(
      (__hip_bfloat16*)R2, B2t, b2, nullptr, (__hip_bfloat16*)R1, 256, 512, 4,
      0, Aadj, inputs, conv_w, conv_b, out);
  // L3 (+ conv chunks 512..1023): y2 -> y3 (R2), Nout=128, K=256, NTN=2
  gemmagg_kernel<<<NTMG * 2 + 512, 256, 0, stream>>>(
      (__hip_bfloat16*)R1, B3t, b3, nullptr, (__hip_bfloat16*)R2, 128, 256, 2,
      512, Aadj, inputs, conv_w, conv_b, out);
  // L4 fused: gemm + agg + knn classifier
  gemm4cls_kernel<<<171, 256, 0, stream>>>(
      (__hip_bfloat16*)R2, B4t, b4, Aadj, knn, cls_w1, cls_b1, prelu_a,
      cls_w2, cls_b2, out + 6291456);
}